// Round 6
// baseline (3483.879 us; speedup 1.0000x reference)
//
#include <hip/hip_runtime.h>
#include <hip/hip_bf16.h>

// Representation_32074815766664 — bf16 I/O (runtime-detected f32 fallback),
// bf16 MFMA internally, f32 accumulation/state.
//
// R6 changes vs R5:
//  - lstm1: c state moved to LDS (f32, stride 516 -> 2-way bank alias only),
//    h carried across the barrier as packed bf16 (24 VGPRs). Arch-VGPR live
//    set ~95 < 128 (the compiler splits the unified file ~evenly between
//    VGPR/AGPR; R2-R5 all spilled because arch state exceeded that half).
//    rows=48 (214 blocks), single h buffer, 2 barriers/t. LDS 152 KB.

typedef __bf16 bf16x8 __attribute__((ext_vector_type(8)));
typedef float f32x4 __attribute__((ext_vector_type(4)));

#define MROWS 10240
#define LDH1  552     // hbuf row stride (bf16), 2-way bank alias only
#define LDC1  516     // cbuf row stride (f32),  2-way bank alias only
#define L1_ROWS 48
#define L1_BLOCKS 214 // ceil(10240/48)

// pf (canonical f32 params) offsets
#define PF_BIAS1   0
#define PF_BIAS2   2048
#define PF_CONDB   4096
#define PF_SAMPB   4352
#define PF_BCAT2   4608
#define PF_B3CAT   5120
#define PF_BN1G    5632
#define PF_BN1B    5888
#define PF_BN2G    6144
#define PF_BN2B    6656
#define PF_BN3G    7168
#define PF_BN3B    7424
#define PF_OW      7680
#define PF_OB      8192
#define PF_TOTAL   8194

__device__ __forceinline__ float fsig(float x) {
  x = fminf(fmaxf(x, -30.0f), 30.0f);
  return 1.0f / (1.0f + __expf(-x));
}
__device__ __forceinline__ float ftanh(float x) {
  x = fminf(fmaxf(x, -15.0f), 15.0f);
  float e = __expf(2.0f * x);
  return (e - 1.0f) / (e + 1.0f);
}
__device__ __forceinline__ bf16x8 bzero8() {
  bf16x8 z;
#pragma unroll
  for (int i = 0; i < 8; ++i) z[i] = (__bf16)0.0f;
  return z;
}
__device__ __forceinline__ float ld_in(const void* p, long i, int bf) {
  return bf ? (float)((const __bf16*)p)[i] : ((const float*)p)[i];
}

// ---------------- detect ----------------
__global__ void detect_kernel(const unsigned* __restrict__ masks, int* __restrict__ flag) {
  if (blockIdx.x == 0 && threadIdx.x == 0)
    *flag = (masks[0] == 0x3F803F80u) ? 1 : 0;
}

// ---------------- prep: canonicalize + swizzle weights ----------------
__global__ void prep_kernel(const int* __restrict__ flagp,
    const void* w_ih1, const void* w_hh1, const void* b_ih1, const void* b_hh1,
    const void* w_ih2, const void* w_hh2, const void* b_ih2, const void* b_hh2,
    const void* t1_w2, const void* t2_w2, const void* t1_b2, const void* t2_b2,
    const void* cond_w, const void* cond_b, const void* sample_w, const void* sample_b,
    const void* bn1_g, const void* bn1_b, const void* bn2_g, const void* bn2_b,
    const void* bn3_g, const void* bn3_b,
    const void* t1_w3, const void* t1_b3, const void* t2_w3, const void* t2_b3,
    const void* t1_ow, const void* t1_ob, const void* t2_ow, const void* t2_ob,
    const void* masks,
    __bf16* __restrict__ w1s, __bf16* __restrict__ w2s,
    __bf16* __restrict__ wcat2, __bf16* __restrict__ cond_w_bf,
    __bf16* __restrict__ sample_w_bf, __bf16* __restrict__ w3cat_bf,
    float* __restrict__ mask_f, float* __restrict__ pf)
{
  const int bf = *flagp;
  const int S1 = 2048 * 544;   // w1s
  const int S2 = 2048 * 1152;  // w2s
  const int S3 = 512 * 512;
  const int S4 = 256 * 512;
  const int S5 = 256 * 1000;
  const int S6 = 512 * 256;
  const int S7 = 10240;
  const int total = S1 + S2 + S3 + S4 + S5 + S6 + S7 + PF_TOTAL;
  for (int idx = blockIdx.x * blockDim.x + threadIdx.x; idx < total;
       idx += gridDim.x * blockDim.x) {
    int i = idx;
    if (i < S1) {
      int e = i & 7, l = (i >> 3) & 63, g = (i >> 9) & 3;
      int grp = i >> 11;               // cgt*17 + kk
      int kk = grp % 17, cgt = grp / 17;
      int colq = l & 15, quad = l >> 4;
      int row = g * 512 + cgt * 16 + colq;
      int k = kk * 32 + quad * 8 + e;
      float v = (k < 512) ? ld_in(w_hh1, (long)row * 512 + k, bf)
              : (k < 525) ? ld_in(w_ih1, (long)row * 13 + (k - 512), bf) : 0.0f;
      w1s[i] = (__bf16)v;
      continue;
    }
    i -= S1;
    if (i < S2) {
      int e = i & 7, l = (i >> 3) & 63, g = (i >> 9) & 3;
      int grp = i >> 11;               // jt*36 + kk
      int kk = grp % 36, jt = grp / 36;
      int colq = l & 15, quad = l >> 4;
      int row = g * 512 + jt * 16 + colq;
      int k = kk * 32 + quad * 8 + e;
      float v = (k < 635) ? ld_in(w_ih2, (long)row * 635 + k, bf)
              : (k < 640) ? 0.0f : ld_in(w_hh2, (long)row * 512 + (k - 640), bf);
      w2s[i] = (__bf16)v;
      continue;
    }
    i -= S2;
    if (i < S3) {
      int r = i >> 9, k = i & 511;
      wcat2[i] = (__bf16)((r < 256) ? ld_in(t1_w2, r * 512 + k, bf)
                                    : ld_in(t2_w2, (r - 256) * 512 + k, bf));
      continue;
    }
    i -= S3;
    if (i < S4) { cond_w_bf[i] = (__bf16)ld_in(cond_w, i, bf); continue; }
    i -= S4;
    if (i < S5) { sample_w_bf[i] = (__bf16)ld_in(sample_w, i, bf); continue; }
    i -= S5;
    if (i < S6) {
      int r = i >> 8, k = i & 255;
      w3cat_bf[i] = (__bf16)((r < 256) ? ld_in(t1_w3, r * 256 + k, bf)
                                       : ld_in(t2_w3, (r - 256) * 256 + k, bf));
      continue;
    }
    i -= S6;
    if (i < S7) { mask_f[i] = ld_in(masks, i, bf); continue; }
    i -= S7;
    {
      int j = i;
      float v;
      if      (j < 2048) v = ld_in(b_ih1, j, bf) + ld_in(b_hh1, j, bf);
      else if (j < 4096) v = ld_in(b_ih2, j - 2048, bf) + ld_in(b_hh2, j - 2048, bf);
      else if (j < 4352) v = ld_in(cond_b, j - 4096, bf);
      else if (j < 4608) v = ld_in(sample_b, j - 4352, bf);
      else if (j < 5120) { int k = j - 4608; v = (k < 256) ? ld_in(t1_b2, k, bf) : ld_in(t2_b2, k - 256, bf); }
      else if (j < 5632) { int k = j - 5120; v = (k < 256) ? ld_in(t1_b3, k, bf) : ld_in(t2_b3, k - 256, bf); }
      else if (j < 5888) v = ld_in(bn1_g, j - 5632, bf);
      else if (j < 6144) v = ld_in(bn1_b, j - 5888, bf);
      else if (j < 6656) v = ld_in(bn2_g, j - 6144, bf);
      else if (j < 7168) v = ld_in(bn2_b, j - 6656, bf);
      else if (j < 7424) v = ld_in(bn3_g, j - 7168, bf);
      else if (j < 7680) v = ld_in(bn3_b, j - 7424, bf);
      else if (j < 8192) { int k = j - 7680; v = (k < 256) ? ld_in(t1_ow, k, bf) : ld_in(t2_ow, k - 256, bf); }
      else v = (j == 8192) ? ld_in(t1_ob, 0, bf) : ld_in(t2_ob, 0, bf);
      pf[j] = v;
    }
  }
}

// ---------------- samples -> bf16 ----------------
__global__ void conv_samples_kernel(const int* __restrict__ flagp,
                                    const void* __restrict__ samples,
                                    __bf16* __restrict__ dst)
{
  const int bf = *flagp;
  for (long i = blockIdx.x * blockDim.x + threadIdx.x; i < 10240000L;
       i += (long)gridDim.x * blockDim.x)
    dst[i] = (__bf16)ld_in(samples, i, bf);
}

// ---------------- featcopy (Astage stride 640) ----------------
__global__ void featcopy_kernel(const int* __restrict__ flagp,
                                const void* __restrict__ ops,
                                const void* __restrict__ extra,
                                __bf16* __restrict__ Astage)
{
  const int bf = *flagp;
  int idx = blockIdx.x * blockDim.x + threadIdx.x;  // exactly 10240*128
  int m = idx >> 7, c = idx & 127;
  float v; int col;
  if (c < 15)       { v = ld_in(ops, (long)m * 15 + c, bf);            col = c; }
  else if (c < 123) { v = ld_in(extra, (long)m * 108 + (c - 15), bf);  col = c; }
  else              { v = 0.0f;                                        col = 512 + c; } // 635..639
  Astage[(size_t)m * 640 + col] = (__bf16)v;
}

// ---------------- fused 10-step LSTM-1; c in LDS, h packed across barrier ----
// 214 blocks x 512 threads (8 waves). Block owns 48 rows; wave owns 64 h-cols.
// hbuf: single-buffered augmented h[48][552] (0..511 h, 512..524 x_t, rest 0).
// cbuf: f32 c-state [48][516]. Two barriers per timestep.
__global__ __launch_bounds__(512, 2) void lstm1_kernel(
    const int* __restrict__ flagp,
    const void* __restrict__ cond1,     // (10240,10,13)
    const __bf16* __restrict__ w1s,     // swizzled (2048x544)
    const float*  __restrict__ bias,    // (2048)
    __bf16* __restrict__ h_out)         // (10272,512) padded
{
  __shared__ __attribute__((aligned(16))) __bf16 hbuf[L1_ROWS * LDH1];
  __shared__ __attribute__((aligned(16))) float  cbuf[L1_ROWS * LDC1];
  const int bf   = *flagp;
  const int tid  = threadIdx.x;
  const int wave = tid >> 6;
  const int lane = tid & 63;
  const int colq = lane & 15;
  const int quad = lane >> 4;
  const int r0   = blockIdx.x * L1_ROWS;

  {
    bf16x8 z8 = bzero8();
    for (int i = tid * 8; i < L1_ROWS * LDH1; i += 512 * 8)
      *(bf16x8*)&hbuf[i] = z8;
    f32x4 z4 = {0.0f, 0.0f, 0.0f, 0.0f};
    for (int i = tid * 4; i < L1_ROWS * LDC1; i += 512 * 4)
      *(f32x4*)&cbuf[i] = z4;
  }
  __syncthreads();
  if (tid < L1_ROWS * 8) {  // stage x_0: 48 rows x 8 lanes
    int row = tid >> 3, jj = tid & 7, gr = r0 + row;
    if (gr < MROWS) {
      long base = (long)gr * 130;
      hbuf[row * LDH1 + 512 + jj] = (__bf16)ld_in(cond1, base + jj, bf);
      if (jj < 5) hbuf[row * LDH1 + 520 + jj] = (__bf16)ld_in(cond1, base + 8 + jj, bf);
    }
  }
  __syncthreads();

  const int jbase = wave * 64;

  float bi4[4], bf4[4], bg4[4], bo4[4];
#pragma unroll
  for (int cg = 0; cg < 4; ++cg) {
    const int jc = jbase + cg * 16 + colq;
    bi4[cg] = bias[jc];
    bf4[cg] = bias[512 + jc];
    bg4[cg] = bias[1024 + jc];
    bo4[cg] = bias[1536 + jc];
  }

  union UP { unsigned u; __bf16 h[2]; };

#pragma unroll 1
  for (int t = 0; t < 10; ++t) {
    unsigned hpack[4][3][2];   // 24 VGPRs: new h as packed bf16 pairs
#pragma unroll
    for (int cg = 0; cg < 4; ++cg) {
      f32x4 acc[3][4];
#pragma unroll
      for (int a = 0; a < 3; ++a)
#pragma unroll
        for (int g = 0; g < 4; ++g)
#pragma unroll
          for (int r = 0; r < 4; ++r) acc[a][g][r] = 0.0f;

      const __bf16* wp = w1s + ((size_t)(wave * 4 + cg) * 17 * 4 * 512) + (lane << 3);
#pragma unroll 2
      for (int kk = 0; kk < 17; ++kk) {
        const int kof = (kk << 5) + (quad << 3);
        bf16x8 af[3];
#pragma unroll
        for (int rt = 0; rt < 3; ++rt)
          af[rt] = *(const bf16x8*)&hbuf[(rt * 16 + colq) * LDH1 + kof];
        bf16x8 bfr[4];
#pragma unroll
        for (int g = 0; g < 4; ++g)
          bfr[g] = *(const bf16x8*)&wp[(kk * 4 + g) << 9];
#pragma unroll
        for (int g = 0; g < 4; ++g)
#pragma unroll
          for (int rt = 0; rt < 3; ++rt)
            acc[rt][g] = __builtin_amdgcn_mfma_f32_16x16x32_bf16(af[rt], bfr[g], acc[rt][g], 0, 0, 0);
      }
#pragma unroll
      for (int rt = 0; rt < 3; ++rt) {
        float hv[4];
#pragma unroll
        for (int r = 0; r < 4; ++r) {
          const int cidx = (rt * 16 + quad * 4 + r) * LDC1 + jbase + cg * 16 + colq;
          float cold = cbuf[cidx];
          float c = fsig(acc[rt][1][r] + bf4[cg]) * cold
                  + fsig(acc[rt][0][r] + bi4[cg]) * ftanh(acc[rt][2][r] + bg4[cg]);
          cbuf[cidx] = c;
          hv[r] = fsig(acc[rt][3][r] + bo4[cg]) * ftanh(c);
        }
        UP a, b;
        a.h[0] = (__bf16)hv[0]; a.h[1] = (__bf16)hv[1];
        b.h[0] = (__bf16)hv[2]; b.h[1] = (__bf16)hv[3];
        hpack[cg][rt][0] = a.u; hpack[cg][rt][1] = b.u;
      }
    }
    __syncthreads();   // all waves done READING hbuf
#pragma unroll
    for (int cg = 0; cg < 4; ++cg)
#pragma unroll
      for (int rt = 0; rt < 3; ++rt)
#pragma unroll
        for (int p = 0; p < 2; ++p) {
          UP u; u.u = hpack[cg][rt][p];
          const int brow = rt * 16 + quad * 4 + p * 2;
          const int jc = jbase + cg * 16 + colq;
          hbuf[brow * LDH1 + jc]       = u.h[0];
          hbuf[(brow + 1) * LDH1 + jc] = u.h[1];
        }
    if (t < 9 && tid < L1_ROWS * 8) {   // stage x_{t+1}
      int row = tid >> 3, jj = tid & 7, gr = r0 + row;
      if (gr < MROWS) {
        long base = ((long)gr * 10 + (t + 1)) * 13;
        hbuf[row * LDH1 + 512 + jj] = (__bf16)ld_in(cond1, base + jj, bf);
        if (jj < 5) hbuf[row * LDH1 + 520 + jj] = (__bf16)ld_in(cond1, base + 8 + jj, bf);
      }
    }
    __syncthreads();
  }

  for (int i = tid; i < L1_ROWS * 64; i += 512) {
    int row = i >> 6;
    int cb  = (i & 63) << 3;
    *(bf16x8*)&h_out[(size_t)(r0 + row) * 512 + cb] = *(const bf16x8*)&hbuf[row * LDH1 + cb];
  }
}

// ---------------- generic MFMA GEMM: out = act(A @ W^T + bias) [* mask] ----------------
template<int ACT, int OUTBF, int MASKED>
__global__ __launch_bounds__(256, 4) void gemm_kernel(
    const __bf16* __restrict__ A, int lda,
    const __bf16* __restrict__ W, int ldw,
    const float* __restrict__ bias,
    float* __restrict__ outf, __bf16* __restrict__ outb, int ldc,
    const float* __restrict__ mask, int K)
{
  const int tid  = threadIdx.x;
  const int wave = tid >> 6;
  const int lane = tid & 63;
  const int colq = lane & 15;
  const int quad = lane >> 4;
  const int m0 = blockIdx.y * 64 + (wave >> 1) * 32;
  const int n0 = blockIdx.x * 64 + (wave & 1) * 32;

  f32x4 acc[2][2];
#pragma unroll
  for (int a = 0; a < 2; ++a)
#pragma unroll
    for (int b = 0; b < 2; ++b)
#pragma unroll
      for (int r = 0; r < 4; ++r) acc[a][b][r] = 0.0f;

  const int nk = (K + 31) >> 5;
  for (int kk = 0; kk < nk; ++kk) {
    const int kof = (kk << 5) + (quad << 3);
    bf16x8 a0, a1, b0, b1;
    if (kof < K) {
      a0 = *(const bf16x8*)&A[(size_t)(m0 + colq) * lda + kof];
      a1 = *(const bf16x8*)&A[(size_t)(m0 + 16 + colq) * lda + kof];
      b0 = *(const bf16x8*)&W[(size_t)(n0 + colq) * ldw + kof];
      b1 = *(const bf16x8*)&W[(size_t)(n0 + 16 + colq) * ldw + kof];
    } else {
      a0 = bzero8(); a1 = a0; b0 = a0; b1 = a0;
    }
    acc[0][0] = __builtin_amdgcn_mfma_f32_16x16x32_bf16(a0, b0, acc[0][0], 0, 0, 0);
    acc[0][1] = __builtin_amdgcn_mfma_f32_16x16x32_bf16(a0, b1, acc[0][1], 0, 0, 0);
    acc[1][0] = __builtin_amdgcn_mfma_f32_16x16x32_bf16(a1, b0, acc[1][0], 0, 0, 0);
    acc[1][1] = __builtin_amdgcn_mfma_f32_16x16x32_bf16(a1, b1, acc[1][1], 0, 0, 0);
  }
#pragma unroll
  for (int ai = 0; ai < 2; ++ai)
#pragma unroll
    for (int bi = 0; bi < 2; ++bi) {
      const int col = n0 + bi * 16 + colq;
      const float bv = bias[col];
#pragma unroll
      for (int r = 0; r < 4; ++r) {
        const int row = m0 + ai * 16 + quad * 4 + r;
        float v = acc[ai][bi][r] + bv;
        if (ACT) v = fmaxf(v, 0.0f);
        if (MASKED) v *= mask[row];
        if (OUTBF) outb[(size_t)row * ldc + col] = (__bf16)v;
        else       outf[(size_t)row * ldc + col] = v;
      }
    }
}

// ---------------- fused tree level: gather + GEMM(K=1152) + cell update ----------------
__global__ __launch_bounds__(256, 4) void treelvl_kernel(
    const __bf16* __restrict__ Alvl,    // (512,640) level features
    const __bf16* __restrict__ w2s,     // swizzled (2048x1152)
    const float* __restrict__ bias,     // 2048
    const int* __restrict__ mapping,    // level's (2,512)
    const __bf16* __restrict__ h_src, const float* __restrict__ c_src,
    __bf16* __restrict__ h_dst, float* __restrict__ c_dst,
    float* __restrict__ h_f32, int first)
{
  const int tid  = threadIdx.x;
  const int wv   = tid >> 6;
  const int lane = tid & 63;
  const int colq = lane & 15;
  const int quad = lane >> 4;
  const int jt = blockIdx.x;
  const int mt = blockIdx.y;
  const int rowA = mt * 64 + wv * 16 + colq;

  int i0 = 0, i1 = 0;
  if (!first) { i0 = mapping[rowA]; i1 = mapping[512 + rowA]; }
  const float s0 = (i0 > 0) ? 0.5f : 0.0f;
  const float s1 = (i1 > 0) ? 0.5f : 0.0f;
  const __bf16* h0p = h_src + (size_t)((i0 > 0 ? i0 : 1) - 1) * 512;
  const __bf16* h1p = h_src + (size_t)((i1 > 0 ? i1 : 1) - 1) * 512;

  f32x4 acc[4];
#pragma unroll
  for (int g = 0; g < 4; ++g)
#pragma unroll
    for (int r = 0; r < 4; ++r) acc[g][r] = 0.0f;

  const __bf16* wbase = w2s + (size_t)jt * 36 * 4 * 512 + (lane << 3);
  const __bf16* arow  = Alvl + (size_t)rowA * 640;

#pragma unroll 4
  for (int kk = 0; kk < 20; ++kk) {          // feature part of K
    const int kof = (kk << 5) + (quad << 3);
    bf16x8 afr = *(const bf16x8*)&arow[kof];
    bf16x8 b0 = *(const bf16x8*)&wbase[(kk * 4 + 0) << 9];
    bf16x8 b1 = *(const bf16x8*)&wbase[(kk * 4 + 1) << 9];
    bf16x8 b2 = *(const bf16x8*)&wbase[(kk * 4 + 2) << 9];
    bf16x8 b3 = *(const bf16x8*)&wbase[(kk * 4 + 3) << 9];
    acc[0] = __builtin_amdgcn_mfma_f32_16x16x32_bf16(afr, b0, acc[0], 0, 0, 0);
    acc[1] = __builtin_amdgcn_mfma_f32_16x16x32_bf16(afr, b1, acc[1], 0, 0, 0);
    acc[2] = __builtin_amdgcn_mfma_f32_16x16x32_bf16(afr, b2, acc[2], 0, 0, 0);
    acc[3] = __builtin_amdgcn_mfma_f32_16x16x32_bf16(afr, b3, acc[3], 0, 0, 0);
  }
#pragma unroll 4
  for (int kk = 20; kk < 36; ++kk) {         // gathered-h part of K
    const int kh = ((kk - 20) << 5) + (quad << 3);
    bf16x8 v0 = *(const bf16x8*)&h0p[kh];
    bf16x8 v1 = *(const bf16x8*)&h1p[kh];
    bf16x8 afr;
#pragma unroll
    for (int e = 0; e < 8; ++e)
      afr[e] = (__bf16)((float)v0[e] * s0 + (float)v1[e] * s1);
    bf16x8 b0 = *(const bf16x8*)&wbase[(kk * 4 + 0) << 9];
    bf16x8 b1 = *(const bf16x8*)&wbase[(kk * 4 + 1) << 9];
    bf16x8 b2 = *(const bf16x8*)&wbase[(kk * 4 + 2) << 9];
    bf16x8 b3 = *(const bf16x8*)&wbase[(kk * 4 + 3) << 9];
    acc[0] = __builtin_amdgcn_mfma_f32_16x16x32_bf16(afr, b0, acc[0], 0, 0, 0);
    acc[1] = __builtin_amdgcn_mfma_f32_16x16x32_bf16(afr, b1, acc[1], 0, 0, 0);
    acc[2] = __builtin_amdgcn_mfma_f32_16x16x32_bf16(afr, b2, acc[2], 0, 0, 0);
    acc[3] = __builtin_amdgcn_mfma_f32_16x16x32_bf16(afr, b3, acc[3], 0, 0, 0);
  }

  // epilogue: i,f,g,o -> c,h
  const int j = jt * 16 + colq;
  const float bi  = bias[j];
  const float bff = bias[512 + j];
  const float bg  = bias[1024 + j];
  const float bo  = bias[1536 + j];
#pragma unroll
  for (int r = 0; r < 4; ++r) {
    const int mrow = mt * 64 + wv * 16 + quad * 4 + r;
    float ci = 0.0f;
    if (!first) {
      int a0 = mapping[mrow], a1 = mapping[512 + mrow];
      if (a0 > 0) ci += c_src[(size_t)(a0 - 1) * 512 + j];
      if (a1 > 0) ci += c_src[(size_t)(a1 - 1) * 512 + j];
      ci *= 0.5f;
    }
    float c = fsig(acc[1][r] + bff) * ci + fsig(acc[0][r] + bi) * ftanh(acc[2][r] + bg);
    float h = fsig(acc[3][r] + bo) * ftanh(c);
    h_dst[(size_t)mrow * 512 + j] = (__bf16)h;
    c_dst[(size_t)mrow * 512 + j] = c;
    h_f32[(size_t)mrow * 512 + j] = h;
  }
}

// ---------------- batchnorm helpers ----------------
__global__ void stats1_kernel(const float* __restrict__ in, int ld, int N,
                              int rows_per_blk, float* __restrict__ partial)
{
  int b = blockIdx.x;
  int r0 = b * rows_per_blk;
  for (int c = threadIdx.x; c < N; c += blockDim.x) {
    float s = 0.0f, sq = 0.0f;
    for (int r = 0; r < rows_per_blk; ++r) {
      float v = in[(size_t)(r0 + r) * ld + c];
      s += v; sq += v * v;
    }
    partial[(size_t)(2 * b) * N + c] = s;
    partial[(size_t)(2 * b + 1) * N + c] = sq;
  }
}

__global__ void stats2_kernel(const float* __restrict__ partial, int nb, int N,
                              float invM, float* __restrict__ stats)
{
  int c = blockIdx.x * blockDim.x + threadIdx.x;
  if (c >= N) return;
  float s = 0.0f, sq = 0.0f;
  for (int b = 0; b < nb; ++b) {
    s  += partial[(size_t)(2 * b) * N + c];
    sq += partial[(size_t)(2 * b + 1) * N + c];
  }
  float mean = s * invM;
  float var  = sq * invM - mean * mean;
  stats[c]     = mean;
  stats[N + c] = rsqrtf(fmaxf(var, 0.0f) + 1e-5f);
}

__global__ void norm_kernel(const float* __restrict__ in, int ldin,
                            const float* __restrict__ stats, int N, int cshift, int gmask,
                            const float* __restrict__ g, const float* __restrict__ b,
                            __bf16* __restrict__ outp, int ldc, int total)
{
  for (int idx = blockIdx.x * blockDim.x + threadIdx.x; idx < total;
       idx += gridDim.x * blockDim.x) {
    int row = idx >> cshift;
    int c = idx & (N - 1);
    float v = (in[(size_t)row * ldin + c] - stats[c]) * stats[N + c];
    int gi = c & gmask;
    v = v * g[gi] + b[gi];
    outp[(size_t)row * ldc + c] = (__bf16)v;
  }
}

// ---------------- output heads ----------------
__global__ void head_kernel(const int* __restrict__ flagp,
                            const __bf16* __restrict__ tmp3,
                            const float* __restrict__ pf,
                            void* __restrict__ outp)
{
  const int bf = *flagp;
  int idx = blockIdx.x * blockDim.x + threadIdx.x;
  if (idx >= 1024) return;
  int which = idx >> 9;
  int n = idx & 511;
  const __bf16* row = tmp3 + (size_t)n * 512 + which * 256;
  const float* ow = pf + PF_OW + which * 256;
  float s = pf[PF_OB + which];
  for (int k = 0; k < 256; ++k) s += (float)row[k] * ow[k];
  float v = fsig(s);
  if (bf) ((__bf16*)outp)[idx] = (__bf16)v;
  else    ((float*)outp)[idx]  = v;
}

// ---------------- launch ----------------
extern "C" void kernel_launch(void* const* d_in, const int* in_sizes, int n_in,
                              void* d_out, int out_size, void* d_ws, size_t ws_size,
                              hipStream_t stream) {
  const void* operators       = d_in[0];
  const void* extra_infos     = d_in[1];
  const void* condition1s     = d_in[2];
  const void* samples         = d_in[4];
  const void* condition_masks = d_in[5];
  const int*  mapping         = (const int*)d_in[6];
  (void)in_sizes; (void)n_in; (void)out_size; (void)ws_size;

  char* ws = (char*)d_ws;
  size_t off = 0;
  auto alloc = [&](size_t bytes) -> void* {
    void* p = ws + off;
    off += (bytes + 255) & ~(size_t)255;
    return p;
  };
  int*    flag     = (int*)   alloc(256);
  __bf16* w1s      = (__bf16*)alloc((size_t)2048 * 544 * 2);
  __bf16* w2s      = (__bf16*)alloc((size_t)2048 * 1152 * 2);
  __bf16* wcat2    = (__bf16*)alloc(512 * 512 * 2);
  __bf16* cond_w_bf   = (__bf16*)alloc(256 * 512 * 2);
  __bf16* sample_w_bf = (__bf16*)alloc(256 * 1000 * 2);
  __bf16* w3cat_bf    = (__bf16*)alloc(512 * 256 * 2);
  float*  mask_f   = (float*) alloc(10240 * 4);
  float*  pf       = (float*) alloc(PF_TOTAL * 4);
  __bf16* samp_bf  = (__bf16*)alloc((size_t)10240 * 1000 * 2);
  __bf16* h_last   = (__bf16*)alloc((size_t)10272 * 512 * 2);
  float*  condtmp  = (float*) alloc((size_t)10240 * 256 * 4);
  __bf16* Astage   = (__bf16*)alloc((size_t)20 * 512 * 640 * 2);
  __bf16* hs0      = (__bf16*)alloc(512 * 512 * 2);
  __bf16* hs1      = (__bf16*)alloc(512 * 512 * 2);
  float*  cs0      = (float*) alloc(512 * 512 * 4);
  float*  cs1      = (float*) alloc(512 * 512 * 4);
  float*  h_f32    = (float*) alloc(512 * 512 * 4);
  __bf16* zbuf     = (__bf16*)alloc(512 * 512 * 2);
  float*  tmp1     = (float*) alloc(512 * 512 * 4);
  __bf16* tmp2     = (__bf16*)alloc(512 * 512 * 2);
  __bf16* tmp3     = (__bf16*)alloc(512 * 512 * 2);
  float*  partial  = (float*) alloc(64 * 2 * 512 * 4);
  float*  statsb   = (float*) alloc(2 * 512 * 4);

  detect_kernel<<<1, 64, 0, stream>>>((const unsigned*)condition_masks, flag);
  prep_kernel<<<4096, 256, 0, stream>>>(flag,
      d_in[7], d_in[8], d_in[9], d_in[10],
      d_in[17], d_in[18], d_in[19], d_in[20],
      d_in[23], d_in[25], d_in[24], d_in[26],
      d_in[13], d_in[14], d_in[11], d_in[12],
      d_in[15], d_in[16], d_in[21], d_in[22],
      d_in[27], d_in[28],
      d_in[29], d_in[30], d_in[31], d_in[32],
      d_in[33], d_in[34], d_in[35], d_in[36],
      condition_masks,
      w1s, w2s, wcat2, cond_w_bf, sample_w_bf, w3cat_bf, mask_f, pf);
  conv_samples_kernel<<<4096, 256, 0, stream>>>(flag, samples, samp_bf);
  featcopy_kernel<<<5120, 256, 0, stream>>>(flag, operators, extra_infos, Astage);
  lstm1_kernel<<<L1_BLOCKS, 512, 0, stream>>>(flag, condition1s, w1s, pf + PF_BIAS1, h_last);

  // cond = bn1(relu(h_last @ cond_w^T + cond_b)) -> Astage cols 123..378
  gemm_kernel<1,0,0><<<dim3(4,160), 256, 0, stream>>>(h_last, 512, cond_w_bf, 512,
      pf + PF_CONDB, condtmp, nullptr, 256, nullptr, 512);
  stats1_kernel<<<64, 256, 0, stream>>>(condtmp, 256, 256, 160, partial);
  stats2_kernel<<<1, 256, 0, stream>>>(partial, 64, 256, 1.0f / 10240.0f, statsb);
  norm_kernel<<<2560, 256, 0, stream>>>(condtmp, 256, statsb, 256, 8, 255,
      pf + PF_BN1G, pf + PF_BN1B, Astage + 123, 640, 10240 * 256);

  // samp = relu(samples @ sample_w^T + sample_b) * mask -> Astage cols 379..634
  gemm_kernel<1,1,1><<<dim3(4,160), 256, 0, stream>>>(samp_bf, 1000, sample_w_bf, 1000,
      pf + PF_SAMPB, nullptr, Astage + 379, 640, mask_f, 1000);

  // tree: lvl 19 (zero state) down to 0; ping-pong state by level parity
  for (int lvl = 19; lvl >= 0; --lvl) {
    __bf16* hd = (lvl & 1) ? hs1 : hs0;
    float*  cd = (lvl & 1) ? cs1 : cs0;
    const __bf16* hsrc = (lvl & 1) ? hs0 : hs1;
    const float*  csrc = (lvl & 1) ? cs0 : cs1;
    treelvl_kernel<<<dim3(32,8), 256, 0, stream>>>(
        Astage + (size_t)lvl * 512 * 640, w2s, pf + PF_BIAS2,
        mapping + lvl * 1024, hsrc, csrc, hd, cd, h_f32, (lvl == 19) ? 1 : 0);
  }

  // z = bn2(hid)
  stats1_kernel<<<8, 256, 0, stream>>>(h_f32, 512, 512, 64, partial);
  stats2_kernel<<<2, 256, 0, stream>>>(partial, 8, 512, 1.0f / 512.0f, statsb);
  norm_kernel<<<256, 256, 0, stream>>>(h_f32, 512, statsb, 512, 9, 511,
      pf + PF_BN2G, pf + PF_BN2B, zbuf, 512, 512 * 512);

  // [t1|t2] = bn3(relu(z @ [t1_w2;t2_w2]^T + b))
  gemm_kernel<1,0,0><<<dim3(8,8), 256, 0, stream>>>(zbuf, 512, wcat2, 512,
      pf + PF_BCAT2, tmp1, nullptr, 512, nullptr, 512);
  stats1_kernel<<<8, 256, 0, stream>>>(tmp1, 512, 512, 64, partial);
  stats2_kernel<<<2, 256, 0, stream>>>(partial, 8, 512, 1.0f / 512.0f, statsb);
  norm_kernel<<<256, 256, 0, stream>>>(tmp1, 512, statsb, 512, 9, 255,
      pf + PF_BN3G, pf + PF_BN3B, tmp2, 512, 512 * 512);

  // relu(t @ w3^T + b3) for both heads
  gemm_kernel<1,1,0><<<dim3(4,8), 256, 0, stream>>>(tmp2, 512, w3cat_bf, 256,
      pf + PF_B3CAT, nullptr, tmp3, 512, nullptr, 256);
  gemm_kernel<1,1,0><<<dim3(4,8), 256, 0, stream>>>(tmp2 + 256, 512, w3cat_bf + 256 * 256, 256,
      pf + PF_B3CAT + 256, nullptr, tmp3 + 256, 512, nullptr, 256);

  head_kernel<<<4, 256, 0, stream>>>(flag, tmp3, pf, d_out);
}

// Round 7
// 1573.723 us; speedup vs baseline: 2.2138x; 2.2138x over previous
//
#include <hip/hip_runtime.h>
#include <hip/hip_bf16.h>

// Representation_32074815766664 — bf16 I/O (runtime-detected f32 fallback),
// bf16 MFMA internally, f32 accumulation/state.
//
// R7: lstm1 reverted VERBATIM to the R2 configuration (empirically best:
// 797 us, FETCH 72MB, WRITE 142MB) after R3-R6 regressions showed every
// structural "improvement" increased spill/L2-miss traffic. Keeps R6's
// fused treelvl kernel (20 launches vs 60), Astage stride 640, swizzled w2s.

typedef __bf16 bf16x8 __attribute__((ext_vector_type(8)));
typedef float f32x4 __attribute__((ext_vector_type(4)));

#define MROWS 10240
#define KAUG1 544
#define LDH1  552     // padded LDS stride (2-way bank aliasing only)
#define L1_ROWS 48
#define L1_BLOCKS 214 // ceil(10240/48)

// pf (canonical f32 params) offsets
#define PF_BIAS1   0
#define PF_BIAS2   2048
#define PF_CONDB   4096
#define PF_SAMPB   4352
#define PF_BCAT2   4608
#define PF_B3CAT   5120
#define PF_BN1G    5632
#define PF_BN1B    5888
#define PF_BN2G    6144
#define PF_BN2B    6656
#define PF_BN3G    7168
#define PF_BN3B    7424
#define PF_OW      7680
#define PF_OB      8192
#define PF_TOTAL   8194

__device__ __forceinline__ float fsig(float x) {
  x = fminf(fmaxf(x, -30.0f), 30.0f);
  return 1.0f / (1.0f + __expf(-x));
}
__device__ __forceinline__ float ftanh(float x) {
  x = fminf(fmaxf(x, -15.0f), 15.0f);
  float e = __expf(2.0f * x);
  return (e - 1.0f) / (e + 1.0f);
}
__device__ __forceinline__ bf16x8 bzero8() {
  bf16x8 z;
#pragma unroll
  for (int i = 0; i < 8; ++i) z[i] = (__bf16)0.0f;
  return z;
}
__device__ __forceinline__ float ld_in(const void* p, long i, int bf) {
  return bf ? (float)((const __bf16*)p)[i] : ((const float*)p)[i];
}

// ---------------- detect ----------------
__global__ void detect_kernel(const unsigned* __restrict__ masks, int* __restrict__ flag) {
  if (blockIdx.x == 0 && threadIdx.x == 0)
    *flag = (masks[0] == 0x3F803F80u) ? 1 : 0;
}

// ---------------- prep: canonicalize; w_aug1 PLAIN (R2 layout), w2s swizzled ----
__global__ void prep_kernel(const int* __restrict__ flagp,
    const void* w_ih1, const void* w_hh1, const void* b_ih1, const void* b_hh1,
    const void* w_ih2, const void* w_hh2, const void* b_ih2, const void* b_hh2,
    const void* t1_w2, const void* t2_w2, const void* t1_b2, const void* t2_b2,
    const void* cond_w, const void* cond_b, const void* sample_w, const void* sample_b,
    const void* bn1_g, const void* bn1_b, const void* bn2_g, const void* bn2_b,
    const void* bn3_g, const void* bn3_b,
    const void* t1_w3, const void* t1_b3, const void* t2_w3, const void* t2_b3,
    const void* t1_ow, const void* t1_ob, const void* t2_ow, const void* t2_ob,
    const void* masks,
    __bf16* __restrict__ w_aug1, __bf16* __restrict__ w2s,
    __bf16* __restrict__ wcat2, __bf16* __restrict__ cond_w_bf,
    __bf16* __restrict__ sample_w_bf, __bf16* __restrict__ w3cat_bf,
    float* __restrict__ mask_f, float* __restrict__ pf)
{
  const int bf = *flagp;
  const int S1 = 2048 * 544;   // w_aug1 plain row-major [2048][544]
  const int S2 = 2048 * 1152;  // w2s swizzled
  const int S3 = 512 * 512;
  const int S4 = 256 * 512;
  const int S5 = 256 * 1000;
  const int S6 = 512 * 256;
  const int S7 = 10240;
  const int total = S1 + S2 + S3 + S4 + S5 + S6 + S7 + PF_TOTAL;
  for (int idx = blockIdx.x * blockDim.x + threadIdx.x; idx < total;
       idx += gridDim.x * blockDim.x) {
    int i = idx;
    if (i < S1) {
      int g = i / 544, k = i % 544;
      float v = (k < 512) ? ld_in(w_hh1, (long)g * 512 + k, bf)
              : (k < 525) ? ld_in(w_ih1, (long)g * 13 + (k - 512), bf) : 0.0f;
      w_aug1[i] = (__bf16)v;
      continue;
    }
    i -= S1;
    if (i < S2) {
      int e = i & 7, l = (i >> 3) & 63, g = (i >> 9) & 3;
      int grp = i >> 11;               // jt*36 + kk
      int kk = grp % 36, jt = grp / 36;
      int colq = l & 15, quad = l >> 4;
      int row = g * 512 + jt * 16 + colq;
      int k = kk * 32 + quad * 8 + e;
      float v = (k < 635) ? ld_in(w_ih2, (long)row * 635 + k, bf)
              : (k < 640) ? 0.0f : ld_in(w_hh2, (long)row * 512 + (k - 640), bf);
      w2s[i] = (__bf16)v;
      continue;
    }
    i -= S2;
    if (i < S3) {
      int r = i >> 9, k = i & 511;
      wcat2[i] = (__bf16)((r < 256) ? ld_in(t1_w2, r * 512 + k, bf)
                                    : ld_in(t2_w2, (r - 256) * 512 + k, bf));
      continue;
    }
    i -= S3;
    if (i < S4) { cond_w_bf[i] = (__bf16)ld_in(cond_w, i, bf); continue; }
    i -= S4;
    if (i < S5) { sample_w_bf[i] = (__bf16)ld_in(sample_w, i, bf); continue; }
    i -= S5;
    if (i < S6) {
      int r = i >> 8, k = i & 255;
      w3cat_bf[i] = (__bf16)((r < 256) ? ld_in(t1_w3, r * 256 + k, bf)
                                       : ld_in(t2_w3, (r - 256) * 256 + k, bf));
      continue;
    }
    i -= S6;
    if (i < S7) { mask_f[i] = ld_in(masks, i, bf); continue; }
    i -= S7;
    {
      int j = i;
      float v;
      if      (j < 2048) v = ld_in(b_ih1, j, bf) + ld_in(b_hh1, j, bf);
      else if (j < 4096) v = ld_in(b_ih2, j - 2048, bf) + ld_in(b_hh2, j - 2048, bf);
      else if (j < 4352) v = ld_in(cond_b, j - 4096, bf);
      else if (j < 4608) v = ld_in(sample_b, j - 4352, bf);
      else if (j < 5120) { int k = j - 4608; v = (k < 256) ? ld_in(t1_b2, k, bf) : ld_in(t2_b2, k - 256, bf); }
      else if (j < 5632) { int k = j - 5120; v = (k < 256) ? ld_in(t1_b3, k, bf) : ld_in(t2_b3, k - 256, bf); }
      else if (j < 5888) v = ld_in(bn1_g, j - 5632, bf);
      else if (j < 6144) v = ld_in(bn1_b, j - 5888, bf);
      else if (j < 6656) v = ld_in(bn2_g, j - 6144, bf);
      else if (j < 7168) v = ld_in(bn2_b, j - 6656, bf);
      else if (j < 7424) v = ld_in(bn3_g, j - 7168, bf);
      else if (j < 7680) v = ld_in(bn3_b, j - 7424, bf);
      else if (j < 8192) { int k = j - 7680; v = (k < 256) ? ld_in(t1_ow, k, bf) : ld_in(t2_ow, k - 256, bf); }
      else v = (j == 8192) ? ld_in(t1_ob, 0, bf) : ld_in(t2_ob, 0, bf);
      pf[j] = v;
    }
  }
}

// ---------------- samples -> bf16 ----------------
__global__ void conv_samples_kernel(const int* __restrict__ flagp,
                                    const void* __restrict__ samples,
                                    __bf16* __restrict__ dst)
{
  const int bf = *flagp;
  for (long i = blockIdx.x * blockDim.x + threadIdx.x; i < 10240000L;
       i += (long)gridDim.x * blockDim.x)
    dst[i] = (__bf16)ld_in(samples, i, bf);
}

// ---------------- featcopy (Astage stride 640) ----------------
__global__ void featcopy_kernel(const int* __restrict__ flagp,
                                const void* __restrict__ ops,
                                const void* __restrict__ extra,
                                __bf16* __restrict__ Astage)
{
  const int bf = *flagp;
  int idx = blockIdx.x * blockDim.x + threadIdx.x;  // exactly 10240*128
  int m = idx >> 7, c = idx & 127;
  float v; int col;
  if (c < 15)       { v = ld_in(ops, (long)m * 15 + c, bf);            col = c; }
  else if (c < 123) { v = ld_in(extra, (long)m * 108 + (c - 15), bf);  col = c; }
  else              { v = 0.0f;                                        col = 512 + c; } // 635..639
  Astage[(size_t)m * 640 + col] = (__bf16)v;
}

// ---------------- fused 10-step LSTM-1 — VERBATIM R2 structure (797 us) -----
// grid 214 x 512 threads (8 waves). Block owns 48 rows. Wave owns 64 hidden cols.
// LDS: augmented h[48][552] (cols 0..511 h, 512..524 x_t, rest 0).
__global__ __launch_bounds__(512, 2) void lstm1_kernel(
    const int* __restrict__ flagp,
    const void* __restrict__ cond1,     // (10240,10,13)
    const __bf16* __restrict__ w_aug,   // plain (2048,544)
    const float*  __restrict__ bias,    // (2048)
    __bf16* __restrict__ h_out)         // (10272,512) padded
{
  __shared__ __attribute__((aligned(16))) __bf16 hbuf[L1_ROWS * LDH1];
  const int bf   = *flagp;
  const int tid  = threadIdx.x;
  const int wave = tid >> 6;
  const int lane = tid & 63;
  const int colq = lane & 15;
  const int quad = lane >> 4;
  const int r0   = blockIdx.x * L1_ROWS;

  {
    bf16x8 z8 = bzero8();
    for (int i = tid * 8; i < L1_ROWS * LDH1; i += 512 * 8)
      *(bf16x8*)&hbuf[i] = z8;
  }
  __syncthreads();
  if (tid < L1_ROWS * 8) {           // stage x_0
    int row = tid >> 3, jj = tid & 7;
    int gr = r0 + row;
    if (gr < MROWS) {
      long base = (long)gr * 130;  // t=0
      hbuf[row * LDH1 + 512 + jj] = (__bf16)ld_in(cond1, base + jj, bf);
      if (jj < 5) hbuf[row * LDH1 + 520 + jj] = (__bf16)ld_in(cond1, base + 8 + jj, bf);
    }
  }
  __syncthreads();

  float c_reg[4][3][4];
#pragma unroll
  for (int a = 0; a < 4; ++a)
#pragma unroll
    for (int b = 0; b < 3; ++b)
#pragma unroll
      for (int r = 0; r < 4; ++r) c_reg[a][b][r] = 0.0f;

  const int jbase = wave * 64;

  for (int t = 0; t < 10; ++t) {
    float hnew[4][3][4];
#pragma unroll
    for (int cg = 0; cg < 4; ++cg) {
      const int jc = jbase + cg * 16;
      f32x4 acc[3][4];
#pragma unroll
      for (int a = 0; a < 3; ++a)
#pragma unroll
        for (int g = 0; g < 4; ++g)
#pragma unroll
          for (int r = 0; r < 4; ++r) acc[a][g][r] = 0.0f;

#pragma unroll 1
      for (int kk = 0; kk < 17; ++kk) {
        const int kof = (kk << 5) + (quad << 3);
        bf16x8 af[3];
#pragma unroll
        for (int rt = 0; rt < 3; ++rt)
          af[rt] = *(const bf16x8*)&hbuf[(rt * 16 + colq) * LDH1 + kof];
        bf16x8 bfr[4];
#pragma unroll
        for (int g = 0; g < 4; ++g)
          bfr[g] = *(const bf16x8*)&w_aug[(size_t)((g << 9) + jc + colq) * KAUG1 + kof];
#pragma unroll
        for (int g = 0; g < 4; ++g)
#pragma unroll
          for (int rt = 0; rt < 3; ++rt)
            acc[rt][g] = __builtin_amdgcn_mfma_f32_16x16x32_bf16(af[rt], bfr[g], acc[rt][g], 0, 0, 0);
      }
      const float bi  = bias[jc + colq];
      const float bff = bias[512 + jc + colq];
      const float bg  = bias[1024 + jc + colq];
      const float bo  = bias[1536 + jc + colq];
#pragma unroll
      for (int rt = 0; rt < 3; ++rt)
#pragma unroll
        for (int r = 0; r < 4; ++r) {
          float c = fsig(acc[rt][1][r] + bff) * c_reg[cg][rt][r]
                  + fsig(acc[rt][0][r] + bi) * ftanh(acc[rt][2][r] + bg);
          c_reg[cg][rt][r] = c;
          hnew[cg][rt][r] = fsig(acc[rt][3][r] + bo) * ftanh(c);
        }
    }
    __syncthreads();   // everyone done READING hbuf
#pragma unroll
    for (int cg = 0; cg < 4; ++cg) {
      const int jc = jbase + cg * 16;
#pragma unroll
      for (int rt = 0; rt < 3; ++rt)
#pragma unroll
        for (int r = 0; r < 4; ++r)
          hbuf[(rt * 16 + quad * 4 + r) * LDH1 + jc + colq] = (__bf16)hnew[cg][rt][r];
    }
    if (t < 9 && tid < L1_ROWS * 8) {   // stage x_{t+1}
      int row = tid >> 3, jj = tid & 7;
      int gr = r0 + row;
      if (gr < MROWS) {
        long base = ((long)gr * 10 + (t + 1)) * 13;
        hbuf[row * LDH1 + 512 + jj] = (__bf16)ld_in(cond1, base + jj, bf);
        if (jj < 5) hbuf[row * LDH1 + 520 + jj] = (__bf16)ld_in(cond1, base + 8 + jj, bf);
      }
    }
    __syncthreads();
  }

  for (int i = tid; i < L1_ROWS * 64; i += 512) {
    int row = i >> 6;
    int cb  = (i & 63) << 3;
    *(bf16x8*)&h_out[(size_t)(r0 + row) * 512 + cb] = *(const bf16x8*)&hbuf[row * LDH1 + cb];
  }
}

// ---------------- generic MFMA GEMM: out = act(A @ W^T + bias) [* mask] ----------------
template<int ACT, int OUTBF, int MASKED>
__global__ __launch_bounds__(256, 4) void gemm_kernel(
    const __bf16* __restrict__ A, int lda,
    const __bf16* __restrict__ W, int ldw,
    const float* __restrict__ bias,
    float* __restrict__ outf, __bf16* __restrict__ outb, int ldc,
    const float* __restrict__ mask, int K)
{
  const int tid  = threadIdx.x;
  const int wave = tid >> 6;
  const int lane = tid & 63;
  const int colq = lane & 15;
  const int quad = lane >> 4;
  const int m0 = blockIdx.y * 64 + (wave >> 1) * 32;
  const int n0 = blockIdx.x * 64 + (wave & 1) * 32;

  f32x4 acc[2][2];
#pragma unroll
  for (int a = 0; a < 2; ++a)
#pragma unroll
    for (int b = 0; b < 2; ++b)
#pragma unroll
      for (int r = 0; r < 4; ++r) acc[a][b][r] = 0.0f;

  const int nk = (K + 31) >> 5;
  for (int kk = 0; kk < nk; ++kk) {
    const int kof = (kk << 5) + (quad << 3);
    bf16x8 a0, a1, b0, b1;
    if (kof < K) {
      a0 = *(const bf16x8*)&A[(size_t)(m0 + colq) * lda + kof];
      a1 = *(const bf16x8*)&A[(size_t)(m0 + 16 + colq) * lda + kof];
      b0 = *(const bf16x8*)&W[(size_t)(n0 + colq) * ldw + kof];
      b1 = *(const bf16x8*)&W[(size_t)(n0 + 16 + colq) * ldw + kof];
    } else {
      a0 = bzero8(); a1 = a0; b0 = a0; b1 = a0;
    }
    acc[0][0] = __builtin_amdgcn_mfma_f32_16x16x32_bf16(a0, b0, acc[0][0], 0, 0, 0);
    acc[0][1] = __builtin_amdgcn_mfma_f32_16x16x32_bf16(a0, b1, acc[0][1], 0, 0, 0);
    acc[1][0] = __builtin_amdgcn_mfma_f32_16x16x32_bf16(a1, b0, acc[1][0], 0, 0, 0);
    acc[1][1] = __builtin_amdgcn_mfma_f32_16x16x32_bf16(a1, b1, acc[1][1], 0, 0, 0);
  }
#pragma unroll
  for (int ai = 0; ai < 2; ++ai)
#pragma unroll
    for (int bi = 0; bi < 2; ++bi) {
      const int col = n0 + bi * 16 + colq;
      const float bv = bias[col];
#pragma unroll
      for (int r = 0; r < 4; ++r) {
        const int row = m0 + ai * 16 + quad * 4 + r;
        float v = acc[ai][bi][r] + bv;
        if (ACT) v = fmaxf(v, 0.0f);
        if (MASKED) v *= mask[row];
        if (OUTBF) outb[(size_t)row * ldc + col] = (__bf16)v;
        else       outf[(size_t)row * ldc + col] = v;
      }
    }
}

// ---------------- fused tree level: gather + GEMM(K=1152) + cell update ----------------
__global__ __launch_bounds__(256, 4) void treelvl_kernel(
    const __bf16* __restrict__ Alvl,    // (512,640) level features
    const __bf16* __restrict__ w2s,     // swizzled (2048x1152)
    const float* __restrict__ bias,     // 2048
    const int* __restrict__ mapping,    // level's (2,512)
    const __bf16* __restrict__ h_src, const float* __restrict__ c_src,
    __bf16* __restrict__ h_dst, float* __restrict__ c_dst,
    float* __restrict__ h_f32, int first)
{
  const int tid  = threadIdx.x;
  const int wv   = tid >> 6;
  const int lane = tid & 63;
  const int colq = lane & 15;
  const int quad = lane >> 4;
  const int jt = blockIdx.x;
  const int mt = blockIdx.y;
  const int rowA = mt * 64 + wv * 16 + colq;

  int i0 = 0, i1 = 0;
  if (!first) { i0 = mapping[rowA]; i1 = mapping[512 + rowA]; }
  const float s0 = (i0 > 0) ? 0.5f : 0.0f;
  const float s1 = (i1 > 0) ? 0.5f : 0.0f;
  const __bf16* h0p = h_src + (size_t)((i0 > 0 ? i0 : 1) - 1) * 512;
  const __bf16* h1p = h_src + (size_t)((i1 > 0 ? i1 : 1) - 1) * 512;

  f32x4 acc[4];
#pragma unroll
  for (int g = 0; g < 4; ++g)
#pragma unroll
    for (int r = 0; r < 4; ++r) acc[g][r] = 0.0f;

  const __bf16* wbase = w2s + (size_t)jt * 36 * 4 * 512 + (lane << 3);
  const __bf16* arow  = Alvl + (size_t)rowA * 640;

#pragma unroll 4
  for (int kk = 0; kk < 20; ++kk) {          // feature part of K
    const int kof = (kk << 5) + (quad << 3);
    bf16x8 afr = *(const bf16x8*)&arow[kof];
    bf16x8 b0 = *(const bf16x8*)&wbase[(kk * 4 + 0) << 9];
    bf16x8 b1 = *(const bf16x8*)&wbase[(kk * 4 + 1) << 9];
    bf16x8 b2 = *(const bf16x8*)&wbase[(kk * 4 + 2) << 9];
    bf16x8 b3 = *(const bf16x8*)&wbase[(kk * 4 + 3) << 9];
    acc[0] = __builtin_amdgcn_mfma_f32_16x16x32_bf16(afr, b0, acc[0], 0, 0, 0);
    acc[1] = __builtin_amdgcn_mfma_f32_16x16x32_bf16(afr, b1, acc[1], 0, 0, 0);
    acc[2] = __builtin_amdgcn_mfma_f32_16x16x32_bf16(afr, b2, acc[2], 0, 0, 0);
    acc[3] = __builtin_amdgcn_mfma_f32_16x16x32_bf16(afr, b3, acc[3], 0, 0, 0);
  }
#pragma unroll 4
  for (int kk = 20; kk < 36; ++kk) {         // gathered-h part of K
    const int kh = ((kk - 20) << 5) + (quad << 3);
    bf16x8 v0 = *(const bf16x8*)&h0p[kh];
    bf16x8 v1 = *(const bf16x8*)&h1p[kh];
    bf16x8 afr;
#pragma unroll
    for (int e = 0; e < 8; ++e)
      afr[e] = (__bf16)((float)v0[e] * s0 + (float)v1[e] * s1);
    bf16x8 b0 = *(const bf16x8*)&wbase[(kk * 4 + 0) << 9];
    bf16x8 b1 = *(const bf16x8*)&wbase[(kk * 4 + 1) << 9];
    bf16x8 b2 = *(const bf16x8*)&wbase[(kk * 4 + 2) << 9];
    bf16x8 b3 = *(const bf16x8*)&wbase[(kk * 4 + 3) << 9];
    acc[0] = __builtin_amdgcn_mfma_f32_16x16x32_bf16(afr, b0, acc[0], 0, 0, 0);
    acc[1] = __builtin_amdgcn_mfma_f32_16x16x32_bf16(afr, b1, acc[1], 0, 0, 0);
    acc[2] = __builtin_amdgcn_mfma_f32_16x16x32_bf16(afr, b2, acc[2], 0, 0, 0);
    acc[3] = __builtin_amdgcn_mfma_f32_16x16x32_bf16(afr, b3, acc[3], 0, 0, 0);
  }

  // epilogue: i,f,g,o -> c,h
  const int j = jt * 16 + colq;
  const float bi  = bias[j];
  const float bff = bias[512 + j];
  const float bg  = bias[1024 + j];
  const float bo  = bias[1536 + j];
#pragma unroll
  for (int r = 0; r < 4; ++r) {
    const int mrow = mt * 64 + wv * 16 + quad * 4 + r;
    float ci = 0.0f;
    if (!first) {
      int a0 = mapping[mrow], a1 = mapping[512 + mrow];
      if (a0 > 0) ci += c_src[(size_t)(a0 - 1) * 512 + j];
      if (a1 > 0) ci += c_src[(size_t)(a1 - 1) * 512 + j];
      ci *= 0.5f;
    }
    float c = fsig(acc[1][r] + bff) * ci + fsig(acc[0][r] + bi) * ftanh(acc[2][r] + bg);
    float h = fsig(acc[3][r] + bo) * ftanh(c);
    h_dst[(size_t)mrow * 512 + j] = (__bf16)h;
    c_dst[(size_t)mrow * 512 + j] = c;
    h_f32[(size_t)mrow * 512 + j] = h;
  }
}

// ---------------- batchnorm helpers ----------------
__global__ void stats1_kernel(const float* __restrict__ in, int ld, int N,
                              int rows_per_blk, float* __restrict__ partial)
{
  int b = blockIdx.x;
  int r0 = b * rows_per_blk;
  for (int c = threadIdx.x; c < N; c += blockDim.x) {
    float s = 0.0f, sq = 0.0f;
    for (int r = 0; r < rows_per_blk; ++r) {
      float v = in[(size_t)(r0 + r) * ld + c];
      s += v; sq += v * v;
    }
    partial[(size_t)(2 * b) * N + c] = s;
    partial[(size_t)(2 * b + 1) * N + c] = sq;
  }
}

__global__ void stats2_kernel(const float* __restrict__ partial, int nb, int N,
                              float invM, float* __restrict__ stats)
{
  int c = blockIdx.x * blockDim.x + threadIdx.x;
  if (c >= N) return;
  float s = 0.0f, sq = 0.0f;
  for (int b = 0; b < nb; ++b) {
    s  += partial[(size_t)(2 * b) * N + c];
    sq += partial[(size_t)(2 * b + 1) * N + c];
  }
  float mean = s * invM;
  float var  = sq * invM - mean * mean;
  stats[c]     = mean;
  stats[N + c] = rsqrtf(fmaxf(var, 0.0f) + 1e-5f);
}

__global__ void norm_kernel(const float* __restrict__ in, int ldin,
                            const float* __restrict__ stats, int N, int cshift, int gmask,
                            const float* __restrict__ g, const float* __restrict__ b,
                            __bf16* __restrict__ outp, int ldc, int total)
{
  for (int idx = blockIdx.x * blockDim.x + threadIdx.x; idx < total;
       idx += gridDim.x * blockDim.x) {
    int row = idx >> cshift;
    int c = idx & (N - 1);
    float v = (in[(size_t)row * ldin + c] - stats[c]) * stats[N + c];
    int gi = c & gmask;
    v = v * g[gi] + b[gi];
    outp[(size_t)row * ldc + c] = (__bf16)v;
  }
}

// ---------------- output heads ----------------
__global__ void head_kernel(const int* __restrict__ flagp,
                            const __bf16* __restrict__ tmp3,
                            const float* __restrict__ pf,
                            void* __restrict__ outp)
{
  const int bf = *flagp;
  int idx = blockIdx.x * blockDim.x + threadIdx.x;
  if (idx >= 1024) return;
  int which = idx >> 9;
  int n = idx & 511;
  const __bf16* row = tmp3 + (size_t)n * 512 + which * 256;
  const float* ow = pf + PF_OW + which * 256;
  float s = pf[PF_OB + which];
  for (int k = 0; k < 256; ++k) s += (float)row[k] * ow[k];
  float v = fsig(s);
  if (bf) ((__bf16*)outp)[idx] = (__bf16)v;
  else    ((float*)outp)[idx]  = v;
}

// ---------------- launch ----------------
extern "C" void kernel_launch(void* const* d_in, const int* in_sizes, int n_in,
                              void* d_out, int out_size, void* d_ws, size_t ws_size,
                              hipStream_t stream) {
  const void* operators       = d_in[0];
  const void* extra_infos     = d_in[1];
  const void* condition1s     = d_in[2];
  const void* samples         = d_in[4];
  const void* condition_masks = d_in[5];
  const int*  mapping         = (const int*)d_in[6];
  (void)in_sizes; (void)n_in; (void)out_size; (void)ws_size;

  char* ws = (char*)d_ws;
  size_t off = 0;
  auto alloc = [&](size_t bytes) -> void* {
    void* p = ws + off;
    off += (bytes + 255) & ~(size_t)255;
    return p;
  };
  int*    flag     = (int*)   alloc(256);
  __bf16* w_aug1   = (__bf16*)alloc((size_t)2048 * 544 * 2);
  __bf16* w2s      = (__bf16*)alloc((size_t)2048 * 1152 * 2);
  __bf16* wcat2    = (__bf16*)alloc(512 * 512 * 2);
  __bf16* cond_w_bf   = (__bf16*)alloc(256 * 512 * 2);
  __bf16* sample_w_bf = (__bf16*)alloc(256 * 1000 * 2);
  __bf16* w3cat_bf    = (__bf16*)alloc(512 * 256 * 2);
  float*  mask_f   = (float*) alloc(10240 * 4);
  float*  pf       = (float*) alloc(PF_TOTAL * 4);
  __bf16* samp_bf  = (__bf16*)alloc((size_t)10240 * 1000 * 2);
  __bf16* h_last   = (__bf16*)alloc((size_t)10272 * 512 * 2);
  float*  condtmp  = (float*) alloc((size_t)10240 * 256 * 4);
  __bf16* Astage   = (__bf16*)alloc((size_t)20 * 512 * 640 * 2);
  __bf16* hs0      = (__bf16*)alloc(512 * 512 * 2);
  __bf16* hs1      = (__bf16*)alloc(512 * 512 * 2);
  float*  cs0      = (float*) alloc(512 * 512 * 4);
  float*  cs1      = (float*) alloc(512 * 512 * 4);
  float*  h_f32    = (float*) alloc(512 * 512 * 4);
  __bf16* zbuf     = (__bf16*)alloc(512 * 512 * 2);
  float*  tmp1     = (float*) alloc(512 * 512 * 4);
  __bf16* tmp2     = (__bf16*)alloc(512 * 512 * 2);
  __bf16* tmp3     = (__bf16*)alloc(512 * 512 * 2);
  float*  partial  = (float*) alloc(64 * 2 * 512 * 4);
  float*  statsb   = (float*) alloc(2 * 512 * 4);

  detect_kernel<<<1, 64, 0, stream>>>((const unsigned*)condition_masks, flag);
  prep_kernel<<<4096, 256, 0, stream>>>(flag,
      d_in[7], d_in[8], d_in[9], d_in[10],
      d_in[17], d_in[18], d_in[19], d_in[20],
      d_in[23], d_in[25], d_in[24], d_in[26],
      d_in[13], d_in[14], d_in[11], d_in[12],
      d_in[15], d_in[16], d_in[21], d_in[22],
      d_in[27], d_in[28],
      d_in[29], d_in[30], d_in[31], d_in[32],
      d_in[33], d_in[34], d_in[35], d_in[36],
      condition_masks,
      w_aug1, w2s, wcat2, cond_w_bf, sample_w_bf, w3cat_bf, mask_f, pf);
  conv_samples_kernel<<<4096, 256, 0, stream>>>(flag, samples, samp_bf);
  featcopy_kernel<<<5120, 256, 0, stream>>>(flag, operators, extra_infos, Astage);
  lstm1_kernel<<<L1_BLOCKS, 512, 0, stream>>>(flag, condition1s, w_aug1, pf + PF_BIAS1, h_last);

  // cond = bn1(relu(h_last @ cond_w^T + cond_b)) -> Astage cols 123..378
  gemm_kernel<1,0,0><<<dim3(4,160), 256, 0, stream>>>(h_last, 512, cond_w_bf, 512,
      pf + PF_CONDB, condtmp, nullptr, 256, nullptr, 512);
  stats1_kernel<<<64, 256, 0, stream>>>(condtmp, 256, 256, 160, partial);
  stats2_kernel<<<1, 256, 0, stream>>>(partial, 64, 256, 1.0f / 10240.0f, statsb);
  norm_kernel<<<2560, 256, 0, stream>>>(condtmp, 256, statsb, 256, 8, 255,
      pf + PF_BN1G, pf + PF_BN1B, Astage + 123, 640, 10240 * 256);

  // samp = relu(samples @ sample_w^T + sample_b) * mask -> Astage cols 379..634
  gemm_kernel<1,1,1><<<dim3(4,160), 256, 0, stream>>>(samp_bf, 1000, sample_w_bf, 1000,
      pf + PF_SAMPB, nullptr, Astage + 379, 640, mask_f, 1000);

  // tree: lvl 19 (zero state) down to 0; ping-pong state by level parity
  for (int lvl = 19; lvl >= 0; --lvl) {
    __bf16* hd = (lvl & 1) ? hs1 : hs0;
    float*  cd = (lvl & 1) ? cs1 : cs0;
    const __bf16* hsrc = (lvl & 1) ? hs0 : hs1;
    const float*  csrc = (lvl & 1) ? cs0 : cs1;
    treelvl_kernel<<<dim3(32,8), 256, 0, stream>>>(
        Astage + (size_t)lvl * 512 * 640, w2s, pf + PF_BIAS2,
        mapping + lvl * 1024, hsrc, csrc, hd, cd, h_f32, (lvl == 19) ? 1 : 0);
  }

  // z = bn2(hid)
  stats1_kernel<<<8, 256, 0, stream>>>(h_f32, 512, 512, 64, partial);
  stats2_kernel<<<2, 256, 0, stream>>>(partial, 8, 512, 1.0f / 512.0f, statsb);
  norm_kernel<<<256, 256, 0, stream>>>(h_f32, 512, statsb, 512, 9, 511,
      pf + PF_BN2G, pf + PF_BN2B, zbuf, 512, 512 * 512);

  // [t1|t2] = bn3(relu(z @ [t1_w2;t2_w2]^T + b))
  gemm_kernel<1,0,0><<<dim3(8,8), 256, 0, stream>>>(zbuf, 512, wcat2, 512,
      pf + PF_BCAT2, tmp1, nullptr, 512, nullptr, 512);
  stats1_kernel<<<8, 256, 0, stream>>>(tmp1, 512, 512, 64, partial);
  stats2_kernel<<<2, 256, 0, stream>>>(partial, 8, 512, 1.0f / 512.0f, statsb);
  norm_kernel<<<256, 256, 0, stream>>>(tmp1, 512, statsb, 512, 9, 255,
      pf + PF_BN3G, pf + PF_BN3B, tmp2, 512, 512 * 512);

  // relu(t @ w3^T + b3) for both heads
  gemm_kernel<1,1,0><<<dim3(4,8), 256, 0, stream>>>(tmp2, 512, w3cat_bf, 256,
      pf + PF_B3CAT, nullptr, tmp3, 512, nullptr, 256);
  gemm_kernel<1,1,0><<<dim3(4,8), 256, 0, stream>>>(tmp2 + 256, 512, w3cat_bf + 256 * 256, 256,
      pf + PF_B3CAT + 256, nullptr, tmp3 + 256, 512, nullptr, 256);

  head_kernel<<<4, 256, 0, stream>>>(flag, tmp3, pf, d_out);
}

// Round 8
// 1254.994 us; speedup vs baseline: 2.7760x; 1.2540x over previous
//
#include <hip/hip_runtime.h>
#include <hip/hip_bf16.h>

// Representation_32074815766664 — bf16 I/O (runtime-detected f32 fallback),
// bf16 MFMA internally, f32 accumulation/state.
//
// R8: single-variable change vs R7 (1574 us, lstm1 794 us):
//  - lstm1: ping-pong h LDS buffer; epilogue writes h DIRECTLY to the next
//    buffer, deleting the hnew[4][3][4] temp (48 VGPRs — the suspected spill
//    source behind WRITE 142MB) and one of the two barriers per timestep.
//    rows=48, plain w_aug layout, loads identical to R7.
//  - everything else VERBATIM R7.

typedef __bf16 bf16x8 __attribute__((ext_vector_type(8)));
typedef float f32x4 __attribute__((ext_vector_type(4)));

#define MROWS 10240
#define KAUG1 544
#define LDH1  552     // padded LDS stride (2-way bank aliasing only)
#define L1_ROWS 48
#define L1_BLOCKS 214 // ceil(10240/48)

// pf (canonical f32 params) offsets
#define PF_BIAS1   0
#define PF_BIAS2   2048
#define PF_CONDB   4096
#define PF_SAMPB   4352
#define PF_BCAT2   4608
#define PF_B3CAT   5120
#define PF_BN1G    5632
#define PF_BN1B    5888
#define PF_BN2G    6144
#define PF_BN2B    6656
#define PF_BN3G    7168
#define PF_BN3B    7424
#define PF_OW      7680
#define PF_OB      8192
#define PF_TOTAL   8194

__device__ __forceinline__ float fsig(float x) {
  x = fminf(fmaxf(x, -30.0f), 30.0f);
  return 1.0f / (1.0f + __expf(-x));
}
__device__ __forceinline__ float ftanh(float x) {
  x = fminf(fmaxf(x, -15.0f), 15.0f);
  float e = __expf(2.0f * x);
  return (e - 1.0f) / (e + 1.0f);
}
__device__ __forceinline__ bf16x8 bzero8() {
  bf16x8 z;
#pragma unroll
  for (int i = 0; i < 8; ++i) z[i] = (__bf16)0.0f;
  return z;
}
__device__ __forceinline__ float ld_in(const void* p, long i, int bf) {
  return bf ? (float)((const __bf16*)p)[i] : ((const float*)p)[i];
}

// ---------------- detect ----------------
__global__ void detect_kernel(const unsigned* __restrict__ masks, int* __restrict__ flag) {
  if (blockIdx.x == 0 && threadIdx.x == 0)
    *flag = (masks[0] == 0x3F803F80u) ? 1 : 0;
}

// ---------------- prep: canonicalize; w_aug1 PLAIN (R2 layout), w2s swizzled ----
__global__ void prep_kernel(const int* __restrict__ flagp,
    const void* w_ih1, const void* w_hh1, const void* b_ih1, const void* b_hh1,
    const void* w_ih2, const void* w_hh2, const void* b_ih2, const void* b_hh2,
    const void* t1_w2, const void* t2_w2, const void* t1_b2, const void* t2_b2,
    const void* cond_w, const void* cond_b, const void* sample_w, const void* sample_b,
    const void* bn1_g, const void* bn1_b, const void* bn2_g, const void* bn2_b,
    const void* bn3_g, const void* bn3_b,
    const void* t1_w3, const void* t1_b3, const void* t2_w3, const void* t2_b3,
    const void* t1_ow, const void* t1_ob, const void* t2_ow, const void* t2_ob,
    const void* masks,
    __bf16* __restrict__ w_aug1, __bf16* __restrict__ w2s,
    __bf16* __restrict__ wcat2, __bf16* __restrict__ cond_w_bf,
    __bf16* __restrict__ sample_w_bf, __bf16* __restrict__ w3cat_bf,
    float* __restrict__ mask_f, float* __restrict__ pf)
{
  const int bf = *flagp;
  const int S1 = 2048 * 544;   // w_aug1 plain row-major [2048][544]
  const int S2 = 2048 * 1152;  // w2s swizzled
  const int S3 = 512 * 512;
  const int S4 = 256 * 512;
  const int S5 = 256 * 1000;
  const int S6 = 512 * 256;
  const int S7 = 10240;
  const int total = S1 + S2 + S3 + S4 + S5 + S6 + S7 + PF_TOTAL;
  for (int idx = blockIdx.x * blockDim.x + threadIdx.x; idx < total;
       idx += gridDim.x * blockDim.x) {
    int i = idx;
    if (i < S1) {
      int g = i / 544, k = i % 544;
      float v = (k < 512) ? ld_in(w_hh1, (long)g * 512 + k, bf)
              : (k < 525) ? ld_in(w_ih1, (long)g * 13 + (k - 512), bf) : 0.0f;
      w_aug1[i] = (__bf16)v;
      continue;
    }
    i -= S1;
    if (i < S2) {
      int e = i & 7, l = (i >> 3) & 63, g = (i >> 9) & 3;
      int grp = i >> 11;               // jt*36 + kk
      int kk = grp % 36, jt = grp / 36;
      int colq = l & 15, quad = l >> 4;
      int row = g * 512 + jt * 16 + colq;
      int k = kk * 32 + quad * 8 + e;
      float v = (k < 635) ? ld_in(w_ih2, (long)row * 635 + k, bf)
              : (k < 640) ? 0.0f : ld_in(w_hh2, (long)row * 512 + (k - 640), bf);
      w2s[i] = (__bf16)v;
      continue;
    }
    i -= S2;
    if (i < S3) {
      int r = i >> 9, k = i & 511;
      wcat2[i] = (__bf16)((r < 256) ? ld_in(t1_w2, r * 512 + k, bf)
                                    : ld_in(t2_w2, (r - 256) * 512 + k, bf));
      continue;
    }
    i -= S3;
    if (i < S4) { cond_w_bf[i] = (__bf16)ld_in(cond_w, i, bf); continue; }
    i -= S4;
    if (i < S5) { sample_w_bf[i] = (__bf16)ld_in(sample_w, i, bf); continue; }
    i -= S5;
    if (i < S6) {
      int r = i >> 8, k = i & 255;
      w3cat_bf[i] = (__bf16)((r < 256) ? ld_in(t1_w3, r * 256 + k, bf)
                                       : ld_in(t2_w3, (r - 256) * 256 + k, bf));
      continue;
    }
    i -= S6;
    if (i < S7) { mask_f[i] = ld_in(masks, i, bf); continue; }
    i -= S7;
    {
      int j = i;
      float v;
      if      (j < 2048) v = ld_in(b_ih1, j, bf) + ld_in(b_hh1, j, bf);
      else if (j < 4096) v = ld_in(b_ih2, j - 2048, bf) + ld_in(b_hh2, j - 2048, bf);
      else if (j < 4352) v = ld_in(cond_b, j - 4096, bf);
      else if (j < 4608) v = ld_in(sample_b, j - 4352, bf);
      else if (j < 5120) { int k = j - 4608; v = (k < 256) ? ld_in(t1_b2, k, bf) : ld_in(t2_b2, k - 256, bf); }
      else if (j < 5632) { int k = j - 5120; v = (k < 256) ? ld_in(t1_b3, k, bf) : ld_in(t2_b3, k - 256, bf); }
      else if (j < 5888) v = ld_in(bn1_g, j - 5632, bf);
      else if (j < 6144) v = ld_in(bn1_b, j - 5888, bf);
      else if (j < 6656) v = ld_in(bn2_g, j - 6144, bf);
      else if (j < 7168) v = ld_in(bn2_b, j - 6656, bf);
      else if (j < 7424) v = ld_in(bn3_g, j - 7168, bf);
      else if (j < 7680) v = ld_in(bn3_b, j - 7424, bf);
      else if (j < 8192) { int k = j - 7680; v = (k < 256) ? ld_in(t1_ow, k, bf) : ld_in(t2_ow, k - 256, bf); }
      else v = (j == 8192) ? ld_in(t1_ob, 0, bf) : ld_in(t2_ob, 0, bf);
      pf[j] = v;
    }
  }
}

// ---------------- samples -> bf16 ----------------
__global__ void conv_samples_kernel(const int* __restrict__ flagp,
                                    const void* __restrict__ samples,
                                    __bf16* __restrict__ dst)
{
  const int bf = *flagp;
  for (long i = blockIdx.x * blockDim.x + threadIdx.x; i < 10240000L;
       i += (long)gridDim.x * blockDim.x)
    dst[i] = (__bf16)ld_in(samples, i, bf);
}

// ---------------- featcopy (Astage stride 640) ----------------
__global__ void featcopy_kernel(const int* __restrict__ flagp,
                                const void* __restrict__ ops,
                                const void* __restrict__ extra,
                                __bf16* __restrict__ Astage)
{
  const int bf = *flagp;
  int idx = blockIdx.x * blockDim.x + threadIdx.x;  // exactly 10240*128
  int m = idx >> 7, c = idx & 127;
  float v; int col;
  if (c < 15)       { v = ld_in(ops, (long)m * 15 + c, bf);            col = c; }
  else if (c < 123) { v = ld_in(extra, (long)m * 108 + (c - 15), bf);  col = c; }
  else              { v = 0.0f;                                        col = 512 + c; } // 635..639
  Astage[(size_t)m * 640 + col] = (__bf16)v;
}

// ---------------- fused 10-step LSTM-1 — R7 + ping-pong h (hnew temp deleted) ----
// grid 214 x 512 threads (8 waves). Block owns 48 rows. Wave owns 64 hidden cols.
// hbuf[2]: augmented h[48][552] (cols 0..511 h, 512..524 x_t, rest 0).
// Epilogue writes h straight into the next buffer; ONE barrier per timestep.
__global__ __launch_bounds__(512, 2) void lstm1_kernel(
    const int* __restrict__ flagp,
    const void* __restrict__ cond1,     // (10240,10,13)
    const __bf16* __restrict__ w_aug,   // plain (2048,544)
    const float*  __restrict__ bias,    // (2048)
    __bf16* __restrict__ h_out)         // (10272,512) padded
{
  __shared__ __attribute__((aligned(16))) __bf16 hbuf[2][L1_ROWS * LDH1];
  const int bf   = *flagp;
  const int tid  = threadIdx.x;
  const int wave = tid >> 6;
  const int lane = tid & 63;
  const int colq = lane & 15;
  const int quad = lane >> 4;
  const int r0   = blockIdx.x * L1_ROWS;

  {
    bf16x8 z8 = bzero8();
    for (int i = tid * 8; i < 2 * L1_ROWS * LDH1; i += 512 * 8)
      *(bf16x8*)&hbuf[0][i] = z8;
  }
  __syncthreads();
  if (tid < L1_ROWS * 8) {           // stage x_0 into buf 0
    int row = tid >> 3, jj = tid & 7;
    int gr = r0 + row;
    if (gr < MROWS) {
      long base = (long)gr * 130;  // t=0
      hbuf[0][row * LDH1 + 512 + jj] = (__bf16)ld_in(cond1, base + jj, bf);
      if (jj < 5) hbuf[0][row * LDH1 + 520 + jj] = (__bf16)ld_in(cond1, base + 8 + jj, bf);
    }
  }
  __syncthreads();

  float c_reg[4][3][4];
#pragma unroll
  for (int a = 0; a < 4; ++a)
#pragma unroll
    for (int b = 0; b < 3; ++b)
#pragma unroll
      for (int r = 0; r < 4; ++r) c_reg[a][b][r] = 0.0f;

  const int jbase = wave * 64;

  for (int t = 0; t < 10; ++t) {
    const __bf16* hcur = hbuf[t & 1];
    __bf16* hnxt = hbuf[(t + 1) & 1];
#pragma unroll
    for (int cg = 0; cg < 4; ++cg) {
      const int jc = jbase + cg * 16;
      f32x4 acc[3][4];
#pragma unroll
      for (int a = 0; a < 3; ++a)
#pragma unroll
        for (int g = 0; g < 4; ++g)
#pragma unroll
          for (int r = 0; r < 4; ++r) acc[a][g][r] = 0.0f;

#pragma unroll 1
      for (int kk = 0; kk < 17; ++kk) {
        const int kof = (kk << 5) + (quad << 3);
        bf16x8 af[3];
#pragma unroll
        for (int rt = 0; rt < 3; ++rt)
          af[rt] = *(const bf16x8*)&hcur[(rt * 16 + colq) * LDH1 + kof];
        bf16x8 bfr[4];
#pragma unroll
        for (int g = 0; g < 4; ++g)
          bfr[g] = *(const bf16x8*)&w_aug[(size_t)((g << 9) + jc + colq) * KAUG1 + kof];
#pragma unroll
        for (int g = 0; g < 4; ++g)
#pragma unroll
          for (int rt = 0; rt < 3; ++rt)
            acc[rt][g] = __builtin_amdgcn_mfma_f32_16x16x32_bf16(af[rt], bfr[g], acc[rt][g], 0, 0, 0);
      }
      const float bi  = bias[jc + colq];
      const float bff = bias[512 + jc + colq];
      const float bg  = bias[1024 + jc + colq];
      const float bo  = bias[1536 + jc + colq];
#pragma unroll
      for (int rt = 0; rt < 3; ++rt)
#pragma unroll
        for (int r = 0; r < 4; ++r) {
          float c = fsig(acc[rt][1][r] + bff) * c_reg[cg][rt][r]
                  + fsig(acc[rt][0][r] + bi) * ftanh(acc[rt][2][r] + bg);
          c_reg[cg][rt][r] = c;
          float h = fsig(acc[rt][3][r] + bo) * ftanh(c);
          hnxt[(rt * 16 + quad * 4 + r) * LDH1 + jc + colq] = (__bf16)h;
        }
    }
    if (t < 9 && tid < L1_ROWS * 8) {   // stage x_{t+1} into next buffer
      int row = tid >> 3, jj = tid & 7;
      int gr = r0 + row;
      if (gr < MROWS) {
        long base = ((long)gr * 10 + (t + 1)) * 13;
        hnxt[row * LDH1 + 512 + jj] = (__bf16)ld_in(cond1, base + jj, bf);
        if (jj < 5) hnxt[row * LDH1 + 520 + jj] = (__bf16)ld_in(cond1, base + 8 + jj, bf);
      }
    }
    __syncthreads();
  }

  // final h is in buffer 0 (t=10 even)
  for (int i = tid; i < L1_ROWS * 64; i += 512) {
    int row = i >> 6;
    int cb  = (i & 63) << 3;
    *(bf16x8*)&h_out[(size_t)(r0 + row) * 512 + cb] = *(const bf16x8*)&hbuf[0][row * LDH1 + cb];
  }
}

// ---------------- generic MFMA GEMM: out = act(A @ W^T + bias) [* mask] ----------------
template<int ACT, int OUTBF, int MASKED>
__global__ __launch_bounds__(256, 4) void gemm_kernel(
    const __bf16* __restrict__ A, int lda,
    const __bf16* __restrict__ W, int ldw,
    const float* __restrict__ bias,
    float* __restrict__ outf, __bf16* __restrict__ outb, int ldc,
    const float* __restrict__ mask, int K)
{
  const int tid  = threadIdx.x;
  const int wave = tid >> 6;
  const int lane = tid & 63;
  const int colq = lane & 15;
  const int quad = lane >> 4;
  const int m0 = blockIdx.y * 64 + (wave >> 1) * 32;
  const int n0 = blockIdx.x * 64 + (wave & 1) * 32;

  f32x4 acc[2][2];
#pragma unroll
  for (int a = 0; a < 2; ++a)
#pragma unroll
    for (int b = 0; b < 2; ++b)
#pragma unroll
      for (int r = 0; r < 4; ++r) acc[a][b][r] = 0.0f;

  const int nk = (K + 31) >> 5;
  for (int kk = 0; kk < nk; ++kk) {
    const int kof = (kk << 5) + (quad << 3);
    bf16x8 a0, a1, b0, b1;
    if (kof < K) {
      a0 = *(const bf16x8*)&A[(size_t)(m0 + colq) * lda + kof];
      a1 = *(const bf16x8*)&A[(size_t)(m0 + 16 + colq) * lda + kof];
      b0 = *(const bf16x8*)&W[(size_t)(n0 + colq) * ldw + kof];
      b1 = *(const bf16x8*)&W[(size_t)(n0 + 16 + colq) * ldw + kof];
    } else {
      a0 = bzero8(); a1 = a0; b0 = a0; b1 = a0;
    }
    acc[0][0] = __builtin_amdgcn_mfma_f32_16x16x32_bf16(a0, b0, acc[0][0], 0, 0, 0);
    acc[0][1] = __builtin_amdgcn_mfma_f32_16x16x32_bf16(a0, b1, acc[0][1], 0, 0, 0);
    acc[1][0] = __builtin_amdgcn_mfma_f32_16x16x32_bf16(a1, b0, acc[1][0], 0, 0, 0);
    acc[1][1] = __builtin_amdgcn_mfma_f32_16x16x32_bf16(a1, b1, acc[1][1], 0, 0, 0);
  }
#pragma unroll
  for (int ai = 0; ai < 2; ++ai)
#pragma unroll
    for (int bi = 0; bi < 2; ++bi) {
      const int col = n0 + bi * 16 + colq;
      const float bv = bias[col];
#pragma unroll
      for (int r = 0; r < 4; ++r) {
        const int row = m0 + ai * 16 + quad * 4 + r;
        float v = acc[ai][bi][r] + bv;
        if (ACT) v = fmaxf(v, 0.0f);
        if (MASKED) v *= mask[row];
        if (OUTBF) outb[(size_t)row * ldc + col] = (__bf16)v;
        else       outf[(size_t)row * ldc + col] = v;
      }
    }
}

// ---------------- fused tree level: gather + GEMM(K=1152) + cell update ----------------
__global__ __launch_bounds__(256, 4) void treelvl_kernel(
    const __bf16* __restrict__ Alvl,    // (512,640) level features
    const __bf16* __restrict__ w2s,     // swizzled (2048x1152)
    const float* __restrict__ bias,     // 2048
    const int* __restrict__ mapping,    // level's (2,512)
    const __bf16* __restrict__ h_src, const float* __restrict__ c_src,
    __bf16* __restrict__ h_dst, float* __restrict__ c_dst,
    float* __restrict__ h_f32, int first)
{
  const int tid  = threadIdx.x;
  const int wv   = tid >> 6;
  const int lane = tid & 63;
  const int colq = lane & 15;
  const int quad = lane >> 4;
  const int jt = blockIdx.x;
  const int mt = blockIdx.y;
  const int rowA = mt * 64 + wv * 16 + colq;

  int i0 = 0, i1 = 0;
  if (!first) { i0 = mapping[rowA]; i1 = mapping[512 + rowA]; }
  const float s0 = (i0 > 0) ? 0.5f : 0.0f;
  const float s1 = (i1 > 0) ? 0.5f : 0.0f;
  const __bf16* h0p = h_src + (size_t)((i0 > 0 ? i0 : 1) - 1) * 512;
  const __bf16* h1p = h_src + (size_t)((i1 > 0 ? i1 : 1) - 1) * 512;

  f32x4 acc[4];
#pragma unroll
  for (int g = 0; g < 4; ++g)
#pragma unroll
    for (int r = 0; r < 4; ++r) acc[g][r] = 0.0f;

  const __bf16* wbase = w2s + (size_t)jt * 36 * 4 * 512 + (lane << 3);
  const __bf16* arow  = Alvl + (size_t)rowA * 640;

#pragma unroll 4
  for (int kk = 0; kk < 20; ++kk) {          // feature part of K
    const int kof = (kk << 5) + (quad << 3);
    bf16x8 afr = *(const bf16x8*)&arow[kof];
    bf16x8 b0 = *(const bf16x8*)&wbase[(kk * 4 + 0) << 9];
    bf16x8 b1 = *(const bf16x8*)&wbase[(kk * 4 + 1) << 9];
    bf16x8 b2 = *(const bf16x8*)&wbase[(kk * 4 + 2) << 9];
    bf16x8 b3 = *(const bf16x8*)&wbase[(kk * 4 + 3) << 9];
    acc[0] = __builtin_amdgcn_mfma_f32_16x16x32_bf16(afr, b0, acc[0], 0, 0, 0);
    acc[1] = __builtin_amdgcn_mfma_f32_16x16x32_bf16(afr, b1, acc[1], 0, 0, 0);
    acc[2] = __builtin_amdgcn_mfma_f32_16x16x32_bf16(afr, b2, acc[2], 0, 0, 0);
    acc[3] = __builtin_amdgcn_mfma_f32_16x16x32_bf16(afr, b3, acc[3], 0, 0, 0);
  }
#pragma unroll 4
  for (int kk = 20; kk < 36; ++kk) {         // gathered-h part of K
    const int kh = ((kk - 20) << 5) + (quad << 3);
    bf16x8 v0 = *(const bf16x8*)&h0p[kh];
    bf16x8 v1 = *(const bf16x8*)&h1p[kh];
    bf16x8 afr;
#pragma unroll
    for (int e = 0; e < 8; ++e)
      afr[e] = (__bf16)((float)v0[e] * s0 + (float)v1[e] * s1);
    bf16x8 b0 = *(const bf16x8*)&wbase[(kk * 4 + 0) << 9];
    bf16x8 b1 = *(const bf16x8*)&wbase[(kk * 4 + 1) << 9];
    bf16x8 b2 = *(const bf16x8*)&wbase[(kk * 4 + 2) << 9];
    bf16x8 b3 = *(const bf16x8*)&wbase[(kk * 4 + 3) << 9];
    acc[0] = __builtin_amdgcn_mfma_f32_16x16x32_bf16(afr, b0, acc[0], 0, 0, 0);
    acc[1] = __builtin_amdgcn_mfma_f32_16x16x32_bf16(afr, b1, acc[1], 0, 0, 0);
    acc[2] = __builtin_amdgcn_mfma_f32_16x16x32_bf16(afr, b2, acc[2], 0, 0, 0);
    acc[3] = __builtin_amdgcn_mfma_f32_16x16x32_bf16(afr, b3, acc[3], 0, 0, 0);
  }

  // epilogue: i,f,g,o -> c,h
  const int j = jt * 16 + colq;
  const float bi  = bias[j];
  const float bff = bias[512 + j];
  const float bg  = bias[1024 + j];
  const float bo  = bias[1536 + j];
#pragma unroll
  for (int r = 0; r < 4; ++r) {
    const int mrow = mt * 64 + wv * 16 + quad * 4 + r;
    float ci = 0.0f;
    if (!first) {
      int a0 = mapping[mrow], a1 = mapping[512 + mrow];
      if (a0 > 0) ci += c_src[(size_t)(a0 - 1) * 512 + j];
      if (a1 > 0) ci += c_src[(size_t)(a1 - 1) * 512 + j];
      ci *= 0.5f;
    }
    float c = fsig(acc[1][r] + bff) * ci + fsig(acc[0][r] + bi) * ftanh(acc[2][r] + bg);
    float h = fsig(acc[3][r] + bo) * ftanh(c);
    h_dst[(size_t)mrow * 512 + j] = (__bf16)h;
    c_dst[(size_t)mrow * 512 + j] = c;
    h_f32[(size_t)mrow * 512 + j] = h;
  }
}

// ---------------- batchnorm helpers ----------------
__global__ void stats1_kernel(const float* __restrict__ in, int ld, int N,
                              int rows_per_blk, float* __restrict__ partial)
{
  int b = blockIdx.x;
  int r0 = b * rows_per_blk;
  for (int c = threadIdx.x; c < N; c += blockDim.x) {
    float s = 0.0f, sq = 0.0f;
    for (int r = 0; r < rows_per_blk; ++r) {
      float v = in[(size_t)(r0 + r) * ld + c];
      s += v; sq += v * v;
    }
    partial[(size_t)(2 * b) * N + c] = s;
    partial[(size_t)(2 * b + 1) * N + c] = sq;
  }
}

__global__ void stats2_kernel(const float* __restrict__ partial, int nb, int N,
                              float invM, float* __restrict__ stats)
{
  int c = blockIdx.x * blockDim.x + threadIdx.x;
  if (c >= N) return;
  float s = 0.0f, sq = 0.0f;
  for (int b = 0; b < nb; ++b) {
    s  += partial[(size_t)(2 * b) * N + c];
    sq += partial[(size_t)(2 * b + 1) * N + c];
  }
  float mean = s * invM;
  float var  = sq * invM - mean * mean;
  stats[c]     = mean;
  stats[N + c] = rsqrtf(fmaxf(var, 0.0f) + 1e-5f);
}

__global__ void norm_kernel(const float* __restrict__ in, int ldin,
                            const float* __restrict__ stats, int N, int cshift, int gmask,
                            const float* __restrict__ g, const float* __restrict__ b,
                            __bf16* __restrict__ outp, int ldc, int total)
{
  for (int idx = blockIdx.x * blockDim.x + threadIdx.x; idx < total;
       idx += gridDim.x * blockDim.x) {
    int row = idx >> cshift;
    int c = idx & (N - 1);
    float v = (in[(size_t)row * ldin + c] - stats[c]) * stats[N + c];
    int gi = c & gmask;
    v = v * g[gi] + b[gi];
    outp[(size_t)row * ldc + c] = (__bf16)v;
  }
}

// ---------------- output heads ----------------
__global__ void head_kernel(const int* __restrict__ flagp,
                            const __bf16* __restrict__ tmp3,
                            const float* __restrict__ pf,
                            void* __restrict__ outp)
{
  const int bf = *flagp;
  int idx = blockIdx.x * blockDim.x + threadIdx.x;
  if (idx >= 1024) return;
  int which = idx >> 9;
  int n = idx & 511;
  const __bf16* row = tmp3 + (size_t)n * 512 + which * 256;
  const float* ow = pf + PF_OW + which * 256;
  float s = pf[PF_OB + which];
  for (int k = 0; k < 256; ++k) s += (float)row[k] * ow[k];
  float v = fsig(s);
  if (bf) ((__bf16*)outp)[idx] = (__bf16)v;
  else    ((float*)outp)[idx]  = v;
}

// ---------------- launch ----------------
extern "C" void kernel_launch(void* const* d_in, const int* in_sizes, int n_in,
                              void* d_out, int out_size, void* d_ws, size_t ws_size,
                              hipStream_t stream) {
  const void* operators       = d_in[0];
  const void* extra_infos     = d_in[1];
  const void* condition1s     = d_in[2];
  const void* samples         = d_in[4];
  const void* condition_masks = d_in[5];
  const int*  mapping         = (const int*)d_in[6];
  (void)in_sizes; (void)n_in; (void)out_size; (void)ws_size;

  char* ws = (char*)d_ws;
  size_t off = 0;
  auto alloc = [&](size_t bytes) -> void* {
    void* p = ws + off;
    off += (bytes + 255) & ~(size_t)255;
    return p;
  };
  int*    flag     = (int*)   alloc(256);
  __bf16* w_aug1   = (__bf16*)alloc((size_t)2048 * 544 * 2);
  __bf16* w2s      = (__bf16*)alloc((size_t)2048 * 1152 * 2);
  __bf16* wcat2    = (__bf16*)alloc(512 * 512 * 2);
  __bf16* cond_w_bf   = (__bf16*)alloc(256 * 512 * 2);
  __bf16* sample_w_bf = (__bf16*)alloc(256 * 1000 * 2);
  __bf16* w3cat_bf    = (__bf16*)alloc(512 * 256 * 2);
  float*  mask_f   = (float*) alloc(10240 * 4);
  float*  pf       = (float*) alloc(PF_TOTAL * 4);
  __bf16* samp_bf  = (__bf16*)alloc((size_t)10240 * 1000 * 2);
  __bf16* h_last   = (__bf16*)alloc((size_t)10272 * 512 * 2);
  float*  condtmp  = (float*) alloc((size_t)10240 * 256 * 4);
  __bf16* Astage   = (__bf16*)alloc((size_t)20 * 512 * 640 * 2);
  __bf16* hs0      = (__bf16*)alloc(512 * 512 * 2);
  __bf16* hs1      = (__bf16*)alloc(512 * 512 * 2);
  float*  cs0      = (float*) alloc(512 * 512 * 4);
  float*  cs1      = (float*) alloc(512 * 512 * 4);
  float*  h_f32    = (float*) alloc(512 * 512 * 4);
  __bf16* zbuf     = (__bf16*)alloc(512 * 512 * 2);
  float*  tmp1     = (float*) alloc(512 * 512 * 4);
  __bf16* tmp2     = (__bf16*)alloc(512 * 512 * 2);
  __bf16* tmp3     = (__bf16*)alloc(512 * 512 * 2);
  float*  partial  = (float*) alloc(64 * 2 * 512 * 4);
  float*  statsb   = (float*) alloc(2 * 512 * 4);

  detect_kernel<<<1, 64, 0, stream>>>((const unsigned*)condition_masks, flag);
  prep_kernel<<<4096, 256, 0, stream>>>(flag,
      d_in[7], d_in[8], d_in[9], d_in[10],
      d_in[17], d_in[18], d_in[19], d_in[20],
      d_in[23], d_in[25], d_in[24], d_in[26],
      d_in[13], d_in[14], d_in[11], d_in[12],
      d_in[15], d_in[16], d_in[21], d_in[22],
      d_in[27], d_in[28],
      d_in[29], d_in[30], d_in[31], d_in[32],
      d_in[33], d_in[34], d_in[35], d_in[36],
      condition_masks,
      w_aug1, w2s, wcat2, cond_w_bf, sample_w_bf, w3cat_bf, mask_f, pf);
  conv_samples_kernel<<<4096, 256, 0, stream>>>(flag, samples, samp_bf);
  featcopy_kernel<<<5120, 256, 0, stream>>>(flag, operators, extra_infos, Astage);
  lstm1_kernel<<<L1_BLOCKS, 512, 0, stream>>>(flag, condition1s, w_aug1, pf + PF_BIAS1, h_last);

  // cond = bn1(relu(h_last @ cond_w^T + cond_b)) -> Astage cols 123..378
  gemm_kernel<1,0,0><<<dim3(4,160), 256, 0, stream>>>(h_last, 512, cond_w_bf, 512,
      pf + PF_CONDB, condtmp, nullptr, 256, nullptr, 512);
  stats1_kernel<<<64, 256, 0, stream>>>(condtmp, 256, 256, 160, partial);
  stats2_kernel<<<1, 256, 0, stream>>>(partial, 64, 256, 1.0f / 10240.0f, statsb);
  norm_kernel<<<2560, 256, 0, stream>>>(condtmp, 256, statsb, 256, 8, 255,
      pf + PF_BN1G, pf + PF_BN1B, Astage + 123, 640, 10240 * 256);

  // samp = relu(samples @ sample_w^T + sample_b) * mask -> Astage cols 379..634
  gemm_kernel<1,1,1><<<dim3(4,160), 256, 0, stream>>>(samp_bf, 1000, sample_w_bf, 1000,
      pf + PF_SAMPB, nullptr, Astage + 379, 640, mask_f, 1000);

  // tree: lvl 19 (zero state) down to 0; ping-pong state by level parity
  for (int lvl = 19; lvl >= 0; --lvl) {
    __bf16* hd = (lvl & 1) ? hs1 : hs0;
    float*  cd = (lvl & 1) ? cs1 : cs0;
    const __bf16* hsrc = (lvl & 1) ? hs0 : hs1;
    const float*  csrc = (lvl & 1) ? cs0 : cs1;
    treelvl_kernel<<<dim3(32,8), 256, 0, stream>>>(
        Astage + (size_t)lvl * 512 * 640, w2s, pf + PF_BIAS2,
        mapping + lvl * 1024, hsrc, csrc, hd, cd, h_f32, (lvl == 19) ? 1 : 0);
  }

  // z = bn2(hid)
  stats1_kernel<<<8, 256, 0, stream>>>(h_f32, 512, 512, 64, partial);
  stats2_kernel<<<2, 256, 0, stream>>>(partial, 8, 512, 1.0f / 512.0f, statsb);
  norm_kernel<<<256, 256, 0, stream>>>(h_f32, 512, statsb, 512, 9, 511,
      pf + PF_BN2G, pf + PF_BN2B, zbuf, 512, 512 * 512);

  // [t1|t2] = bn3(relu(z @ [t1_w2;t2_w2]^T + b))
  gemm_kernel<1,0,0><<<dim3(8,8), 256, 0, stream>>>(zbuf, 512, wcat2, 512,
      pf + PF_BCAT2, tmp1, nullptr, 512, nullptr, 512);
  stats1_kernel<<<8, 256, 0, stream>>>(tmp1, 512, 512, 64, partial);
  stats2_kernel<<<2, 256, 0, stream>>>(partial, 8, 512, 1.0f / 512.0f, statsb);
  norm_kernel<<<256, 256, 0, stream>>>(tmp1, 512, statsb, 512, 9, 255,
      pf + PF_BN3G, pf + PF_BN3B, tmp2, 512, 512 * 512);

  // relu(t @ w3^T + b3) for both heads
  gemm_kernel<1,1,0><<<dim3(4,8), 256, 0, stream>>>(tmp2, 512, w3cat_bf, 256,
      pf + PF_B3CAT, nullptr, tmp3, 512, nullptr, 256);
  gemm_kernel<1,1,0><<<dim3(4,8), 256, 0, stream>>>(tmp2 + 256, 512, w3cat_bf + 256 * 256, 256,
      pf + PF_B3CAT + 256, nullptr, tmp3 + 256, 512, nullptr, 256);

  head_kernel<<<4, 256, 0, stream>>>(flag, tmp3, pf, d_out);
}

// Round 9
// 1153.660 us; speedup vs baseline: 3.0198x; 1.0878x over previous
//
#include <hip/hip_runtime.h>
#include <hip/hip_bf16.h>

// Representation_32074815766664 — bf16 I/O (runtime-detected f32 fallback),
// bf16 MFMA internally, f32 accumulation/state.
//
// R9 changes vs R8 (1255 us; lstm1 499 us, no spill):
//  - lstm1: swizzled w1s layout — each B-fragment load becomes one
//    lane-contiguous 1KB read with constant offsets (R8: 16 scattered 64B
//    lines + 64-bit addr math per load; VALUBusy 39%). rows=48 / ping-pong /
//    unroll 1 unchanged (the R3 confound removed).
//  - samples GEMM reads the bf16 input directly (flag-selected); the 20MB
//    conv_samples copy early-outs when inputs are bf16.

typedef __bf16 bf16x8 __attribute__((ext_vector_type(8)));
typedef float f32x4 __attribute__((ext_vector_type(4)));

#define MROWS 10240
#define LDH1  552     // padded LDS stride (2-way bank aliasing only)
#define L1_ROWS 48
#define L1_BLOCKS 214 // ceil(10240/48)

// pf (canonical f32 params) offsets
#define PF_BIAS1   0
#define PF_BIAS2   2048
#define PF_CONDB   4096
#define PF_SAMPB   4352
#define PF_BCAT2   4608
#define PF_B3CAT   5120
#define PF_BN1G    5632
#define PF_BN1B    5888
#define PF_BN2G    6144
#define PF_BN2B    6656
#define PF_BN3G    7168
#define PF_BN3B    7424
#define PF_OW      7680
#define PF_OB      8192
#define PF_TOTAL   8194

__device__ __forceinline__ float fsig(float x) {
  x = fminf(fmaxf(x, -30.0f), 30.0f);
  return 1.0f / (1.0f + __expf(-x));
}
__device__ __forceinline__ float ftanh(float x) {
  x = fminf(fmaxf(x, -15.0f), 15.0f);
  float e = __expf(2.0f * x);
  return (e - 1.0f) / (e + 1.0f);
}
__device__ __forceinline__ bf16x8 bzero8() {
  bf16x8 z;
#pragma unroll
  for (int i = 0; i < 8; ++i) z[i] = (__bf16)0.0f;
  return z;
}
__device__ __forceinline__ float ld_in(const void* p, long i, int bf) {
  return bf ? (float)((const __bf16*)p)[i] : ((const float*)p)[i];
}

// ---------------- detect ----------------
__global__ void detect_kernel(const unsigned* __restrict__ masks, int* __restrict__ flag) {
  if (blockIdx.x == 0 && threadIdx.x == 0)
    *flag = (masks[0] == 0x3F803F80u) ? 1 : 0;
}

// ---------------- prep: canonicalize; w1s swizzled, w2s swizzled ----------------
// w1s: elem((cgt*17+kk)*4+g, lane, e) = w_aug1[g*512+cgt*16+(lane&15)][kk*32+(lane>>4)*8+e]
__global__ void prep_kernel(const int* __restrict__ flagp,
    const void* w_ih1, const void* w_hh1, const void* b_ih1, const void* b_hh1,
    const void* w_ih2, const void* w_hh2, const void* b_ih2, const void* b_hh2,
    const void* t1_w2, const void* t2_w2, const void* t1_b2, const void* t2_b2,
    const void* cond_w, const void* cond_b, const void* sample_w, const void* sample_b,
    const void* bn1_g, const void* bn1_b, const void* bn2_g, const void* bn2_b,
    const void* bn3_g, const void* bn3_b,
    const void* t1_w3, const void* t1_b3, const void* t2_w3, const void* t2_b3,
    const void* t1_ow, const void* t1_ob, const void* t2_ow, const void* t2_ob,
    const void* masks,
    __bf16* __restrict__ w1s, __bf16* __restrict__ w2s,
    __bf16* __restrict__ wcat2, __bf16* __restrict__ cond_w_bf,
    __bf16* __restrict__ sample_w_bf, __bf16* __restrict__ w3cat_bf,
    float* __restrict__ mask_f, float* __restrict__ pf)
{
  const int bf = *flagp;
  const int S1 = 2048 * 544;   // w1s swizzled
  const int S2 = 2048 * 1152;  // w2s swizzled
  const int S3 = 512 * 512;
  const int S4 = 256 * 512;
  const int S5 = 256 * 1000;
  const int S6 = 512 * 256;
  const int S7 = 10240;
  const int total = S1 + S2 + S3 + S4 + S5 + S6 + S7 + PF_TOTAL;
  for (int idx = blockIdx.x * blockDim.x + threadIdx.x; idx < total;
       idx += gridDim.x * blockDim.x) {
    int i = idx;
    if (i < S1) {
      int e = i & 7, l = (i >> 3) & 63, g = (i >> 9) & 3;
      int grp = i >> 11;               // cgt*17 + kk
      int kk = grp % 17, cgt = grp / 17;
      int colq = l & 15, quad = l >> 4;
      int row = g * 512 + cgt * 16 + colq;
      int k = kk * 32 + quad * 8 + e;
      float v = (k < 512) ? ld_in(w_hh1, (long)row * 512 + k, bf)
              : (k < 525) ? ld_in(w_ih1, (long)row * 13 + (k - 512), bf) : 0.0f;
      w1s[i] = (__bf16)v;
      continue;
    }
    i -= S1;
    if (i < S2) {
      int e = i & 7, l = (i >> 3) & 63, g = (i >> 9) & 3;
      int grp = i >> 11;               // jt*36 + kk
      int kk = grp % 36, jt = grp / 36;
      int colq = l & 15, quad = l >> 4;
      int row = g * 512 + jt * 16 + colq;
      int k = kk * 32 + quad * 8 + e;
      float v = (k < 635) ? ld_in(w_ih2, (long)row * 635 + k, bf)
              : (k < 640) ? 0.0f : ld_in(w_hh2, (long)row * 512 + (k - 640), bf);
      w2s[i] = (__bf16)v;
      continue;
    }
    i -= S2;
    if (i < S3) {
      int r = i >> 9, k = i & 511;
      wcat2[i] = (__bf16)((r < 256) ? ld_in(t1_w2, r * 512 + k, bf)
                                    : ld_in(t2_w2, (r - 256) * 512 + k, bf));
      continue;
    }
    i -= S3;
    if (i < S4) { cond_w_bf[i] = (__bf16)ld_in(cond_w, i, bf); continue; }
    i -= S4;
    if (i < S5) { sample_w_bf[i] = (__bf16)ld_in(sample_w, i, bf); continue; }
    i -= S5;
    if (i < S6) {
      int r = i >> 8, k = i & 255;
      w3cat_bf[i] = (__bf16)((r < 256) ? ld_in(t1_w3, r * 256 + k, bf)
                                       : ld_in(t2_w3, (r - 256) * 256 + k, bf));
      continue;
    }
    i -= S6;
    if (i < S7) { mask_f[i] = ld_in(masks, i, bf); continue; }
    i -= S7;
    {
      int j = i;
      float v;
      if      (j < 2048) v = ld_in(b_ih1, j, bf) + ld_in(b_hh1, j, bf);
      else if (j < 4096) v = ld_in(b_ih2, j - 2048, bf) + ld_in(b_hh2, j - 2048, bf);
      else if (j < 4352) v = ld_in(cond_b, j - 4096, bf);
      else if (j < 4608) v = ld_in(sample_b, j - 4352, bf);
      else if (j < 5120) { int k = j - 4608; v = (k < 256) ? ld_in(t1_b2, k, bf) : ld_in(t2_b2, k - 256, bf); }
      else if (j < 5632) { int k = j - 5120; v = (k < 256) ? ld_in(t1_b3, k, bf) : ld_in(t2_b3, k - 256, bf); }
      else if (j < 5888) v = ld_in(bn1_g, j - 5632, bf);
      else if (j < 6144) v = ld_in(bn1_b, j - 5888, bf);
      else if (j < 6656) v = ld_in(bn2_g, j - 6144, bf);
      else if (j < 7168) v = ld_in(bn2_b, j - 6656, bf);
      else if (j < 7424) v = ld_in(bn3_g, j - 7168, bf);
      else if (j < 7680) v = ld_in(bn3_b, j - 7424, bf);
      else if (j < 8192) { int k = j - 7680; v = (k < 256) ? ld_in(t1_ow, k, bf) : ld_in(t2_ow, k - 256, bf); }
      else v = (j == 8192) ? ld_in(t1_ob, 0, bf) : ld_in(t2_ob, 0, bf);
      pf[j] = v;
    }
  }
}

// ---------------- samples -> bf16 (only needed on f32 path) ----------------
__global__ void conv_samples_kernel(const int* __restrict__ flagp,
                                    const void* __restrict__ samples,
                                    __bf16* __restrict__ dst)
{
  const int bf = *flagp;
  if (bf) return;   // bf16 input is already the matrix the GEMM reads
  for (long i = blockIdx.x * blockDim.x + threadIdx.x; i < 10240000L;
       i += (long)gridDim.x * blockDim.x)
    dst[i] = (__bf16)ld_in(samples, i, bf);
}

// ---------------- featcopy (Astage stride 640) ----------------
__global__ void featcopy_kernel(const int* __restrict__ flagp,
                                const void* __restrict__ ops,
                                const void* __restrict__ extra,
                                __bf16* __restrict__ Astage)
{
  const int bf = *flagp;
  int idx = blockIdx.x * blockDim.x + threadIdx.x;  // exactly 10240*128
  int m = idx >> 7, c = idx & 127;
  float v; int col;
  if (c < 15)       { v = ld_in(ops, (long)m * 15 + c, bf);            col = c; }
  else if (c < 123) { v = ld_in(extra, (long)m * 108 + (c - 15), bf);  col = c; }
  else              { v = 0.0f;                                        col = 512 + c; } // 635..639
  Astage[(size_t)m * 640 + col] = (__bf16)v;
}

// ---------------- fused 10-step LSTM-1 — R8 + swizzled weights ----------------
// grid 214 x 512 threads (8 waves). Block owns 48 rows. Wave owns 64 hidden cols.
// hbuf[2]: augmented h[48][552]. One barrier per timestep.
__global__ __launch_bounds__(512, 2) void lstm1_kernel(
    const int* __restrict__ flagp,
    const void* __restrict__ cond1,     // (10240,10,13)
    const __bf16* __restrict__ w1s,     // swizzled (2048x544)
    const float*  __restrict__ bias,    // (2048)
    __bf16* __restrict__ h_out)         // (10272,512) padded
{
  __shared__ __attribute__((aligned(16))) __bf16 hbuf[2][L1_ROWS * LDH1];
  const int bf   = *flagp;
  const int tid  = threadIdx.x;
  const int wave = tid >> 6;
  const int lane = tid & 63;
  const int colq = lane & 15;
  const int quad = lane >> 4;
  const int r0   = blockIdx.x * L1_ROWS;

  {
    bf16x8 z8 = bzero8();
    for (int i = tid * 8; i < 2 * L1_ROWS * LDH1; i += 512 * 8)
      *(bf16x8*)&hbuf[0][i] = z8;
  }
  __syncthreads();
  if (tid < L1_ROWS * 8) {           // stage x_0 into buf 0
    int row = tid >> 3, jj = tid & 7;
    int gr = r0 + row;
    if (gr < MROWS) {
      long base = (long)gr * 130;  // t=0
      hbuf[0][row * LDH1 + 512 + jj] = (__bf16)ld_in(cond1, base + jj, bf);
      if (jj < 5) hbuf[0][row * LDH1 + 520 + jj] = (__bf16)ld_in(cond1, base + 8 + jj, bf);
    }
  }
  __syncthreads();

  float c_reg[4][3][4];
#pragma unroll
  for (int a = 0; a < 4; ++a)
#pragma unroll
    for (int b = 0; b < 3; ++b)
#pragma unroll
      for (int r = 0; r < 4; ++r) c_reg[a][b][r] = 0.0f;

  const int jbase = wave * 64;

  for (int t = 0; t < 10; ++t) {
    const __bf16* hcur = hbuf[t & 1];
    __bf16* hnxt = hbuf[(t + 1) & 1];
#pragma unroll
    for (int cg = 0; cg < 4; ++cg) {
      const int jc = jbase + cg * 16;
      f32x4 acc[3][4];
#pragma unroll
      for (int a = 0; a < 3; ++a)
#pragma unroll
        for (int g = 0; g < 4; ++g)
#pragma unroll
          for (int r = 0; r < 4; ++r) acc[a][g][r] = 0.0f;

      const __bf16* wp = w1s + ((size_t)(wave * 4 + cg) * 17 * 4 * 512) + (lane << 3);
#pragma unroll 1
      for (int kk = 0; kk < 17; ++kk) {
        const int kof = (kk << 5) + (quad << 3);
        bf16x8 af[3];
#pragma unroll
        for (int rt = 0; rt < 3; ++rt)
          af[rt] = *(const bf16x8*)&hcur[(rt * 16 + colq) * LDH1 + kof];
        bf16x8 bfr[4];
#pragma unroll
        for (int g = 0; g < 4; ++g)
          bfr[g] = *(const bf16x8*)&wp[(kk * 4 + g) << 9];
#pragma unroll
        for (int g = 0; g < 4; ++g)
#pragma unroll
          for (int rt = 0; rt < 3; ++rt)
            acc[rt][g] = __builtin_amdgcn_mfma_f32_16x16x32_bf16(af[rt], bfr[g], acc[rt][g], 0, 0, 0);
      }
      const float bi  = bias[jc + colq];
      const float bff = bias[512 + jc + colq];
      const float bg  = bias[1024 + jc + colq];
      const float bo  = bias[1536 + jc + colq];
#pragma unroll
      for (int rt = 0; rt < 3; ++rt)
#pragma unroll
        for (int r = 0; r < 4; ++r) {
          float c = fsig(acc[rt][1][r] + bff) * c_reg[cg][rt][r]
                  + fsig(acc[rt][0][r] + bi) * ftanh(acc[rt][2][r] + bg);
          c_reg[cg][rt][r] = c;
          float h = fsig(acc[rt][3][r] + bo) * ftanh(c);
          hnxt[(rt * 16 + quad * 4 + r) * LDH1 + jc + colq] = (__bf16)h;
        }
    }
    if (t < 9 && tid < L1_ROWS * 8) {   // stage x_{t+1} into next buffer
      int row = tid >> 3, jj = tid & 7;
      int gr = r0 + row;
      if (gr < MROWS) {
        long base = ((long)gr * 10 + (t + 1)) * 13;
        hnxt[row * LDH1 + 512 + jj] = (__bf16)ld_in(cond1, base + jj, bf);
        if (jj < 5) hnxt[row * LDH1 + 520 + jj] = (__bf16)ld_in(cond1, base + 8 + jj, bf);
      }
    }
    __syncthreads();
  }

  // final h is in buffer 0 (t=10 even)
  for (int i = tid; i < L1_ROWS * 64; i += 512) {
    int row = i >> 6;
    int cb  = (i & 63) << 3;
    *(bf16x8*)&h_out[(size_t)(r0 + row) * 512 + cb] = *(const bf16x8*)&hbuf[0][row * LDH1 + cb];
  }
}

// ---------------- generic MFMA GEMM: out = act(A @ W^T + bias) [* mask] ----------------
template<int ACT, int OUTBF, int MASKED>
__global__ __launch_bounds__(256, 4) void gemm_kernel(
    const __bf16* __restrict__ A, int lda,
    const __bf16* __restrict__ W, int ldw,
    const float* __restrict__ bias,
    float* __restrict__ outf, __bf16* __restrict__ outb, int ldc,
    const float* __restrict__ mask, int K)
{
  const int tid  = threadIdx.x;
  const int wave = tid >> 6;
  const int lane = tid & 63;
  const int colq = lane & 15;
  const int quad = lane >> 4;
  const int m0 = blockIdx.y * 64 + (wave >> 1) * 32;
  const int n0 = blockIdx.x * 64 + (wave & 1) * 32;

  f32x4 acc[2][2];
#pragma unroll
  for (int a = 0; a < 2; ++a)
#pragma unroll
    for (int b = 0; b < 2; ++b)
#pragma unroll
      for (int r = 0; r < 4; ++r) acc[a][b][r] = 0.0f;

  const int nk = (K + 31) >> 5;
  for (int kk = 0; kk < nk; ++kk) {
    const int kof = (kk << 5) + (quad << 3);
    bf16x8 a0, a1, b0, b1;
    if (kof < K) {
      a0 = *(const bf16x8*)&A[(size_t)(m0 + colq) * lda + kof];
      a1 = *(const bf16x8*)&A[(size_t)(m0 + 16 + colq) * lda + kof];
      b0 = *(const bf16x8*)&W[(size_t)(n0 + colq) * ldw + kof];
      b1 = *(const bf16x8*)&W[(size_t)(n0 + 16 + colq) * ldw + kof];
    } else {
      a0 = bzero8(); a1 = a0; b0 = a0; b1 = a0;
    }
    acc[0][0] = __builtin_amdgcn_mfma_f32_16x16x32_bf16(a0, b0, acc[0][0], 0, 0, 0);
    acc[0][1] = __builtin_amdgcn_mfma_f32_16x16x32_bf16(a0, b1, acc[0][1], 0, 0, 0);
    acc[1][0] = __builtin_amdgcn_mfma_f32_16x16x32_bf16(a1, b0, acc[1][0], 0, 0, 0);
    acc[1][1] = __builtin_amdgcn_mfma_f32_16x16x32_bf16(a1, b1, acc[1][1], 0, 0, 0);
  }
#pragma unroll
  for (int ai = 0; ai < 2; ++ai)
#pragma unroll
    for (int bi = 0; bi < 2; ++bi) {
      const int col = n0 + bi * 16 + colq;
      const float bv = bias[col];
#pragma unroll
      for (int r = 0; r < 4; ++r) {
        const int row = m0 + ai * 16 + quad * 4 + r;
        float v = acc[ai][bi][r] + bv;
        if (ACT) v = fmaxf(v, 0.0f);
        if (MASKED) v *= mask[row];
        if (OUTBF) outb[(size_t)row * ldc + col] = (__bf16)v;
        else       outf[(size_t)row * ldc + col] = v;
      }
    }
}

// ---------------- samples GEMM: A chosen by dtype flag ----------------
// out = relu(A @ W^T + b) * mask -> Astage cols 379..634 (ldc 640), K=1000.
__global__ __launch_bounds__(256, 4) void sampgemm_kernel(
    const int* __restrict__ flagp,
    const void* __restrict__ samples_raw,   // bf16 path reads this directly
    const __bf16* __restrict__ samp_bf,     // f32 path: converted copy
    const __bf16* __restrict__ W,
    const float* __restrict__ bias,
    __bf16* __restrict__ outb,
    const float* __restrict__ mask)
{
  const __bf16* A = (*flagp) ? (const __bf16*)samples_raw : samp_bf;
  const int tid  = threadIdx.x;
  const int wave = tid >> 6;
  const int lane = tid & 63;
  const int colq = lane & 15;
  const int quad = lane >> 4;
  const int m0 = blockIdx.y * 64 + (wave >> 1) * 32;
  const int n0 = blockIdx.x * 64 + (wave & 1) * 32;
  const int K = 1000;

  f32x4 acc[2][2];
#pragma unroll
  for (int a = 0; a < 2; ++a)
#pragma unroll
    for (int b = 0; b < 2; ++b)
#pragma unroll
      for (int r = 0; r < 4; ++r) acc[a][b][r] = 0.0f;

  for (int kk = 0; kk < 32; ++kk) {
    const int kof = (kk << 5) + (quad << 3);
    bf16x8 a0, a1, b0, b1;
    if (kof < K) {
      a0 = *(const bf16x8*)&A[(size_t)(m0 + colq) * 1000 + kof];
      a1 = *(const bf16x8*)&A[(size_t)(m0 + 16 + colq) * 1000 + kof];
      b0 = *(const bf16x8*)&W[(size_t)(n0 + colq) * 1000 + kof];
      b1 = *(const bf16x8*)&W[(size_t)(n0 + 16 + colq) * 1000 + kof];
    } else {
      a0 = bzero8(); a1 = a0; b0 = a0; b1 = a0;
    }
    acc[0][0] = __builtin_amdgcn_mfma_f32_16x16x32_bf16(a0, b0, acc[0][0], 0, 0, 0);
    acc[0][1] = __builtin_amdgcn_mfma_f32_16x16x32_bf16(a0, b1, acc[0][1], 0, 0, 0);
    acc[1][0] = __builtin_amdgcn_mfma_f32_16x16x32_bf16(a1, b0, acc[1][0], 0, 0, 0);
    acc[1][1] = __builtin_amdgcn_mfma_f32_16x16x32_bf16(a1, b1, acc[1][1], 0, 0, 0);
  }
#pragma unroll
  for (int ai = 0; ai < 2; ++ai)
#pragma unroll
    for (int bi = 0; bi < 2; ++bi) {
      const int col = n0 + bi * 16 + colq;
      const float bv = bias[col];
#pragma unroll
      for (int r = 0; r < 4; ++r) {
        const int row = m0 + ai * 16 + quad * 4 + r;
        float v = fmaxf(acc[ai][bi][r] + bv, 0.0f) * mask[row];
        outb[(size_t)row * 640 + col] = (__bf16)v;
      }
    }
}

// ---------------- fused tree level: gather + GEMM(K=1152) + cell update ----------------
__global__ __launch_bounds__(256, 4) void treelvl_kernel(
    const __bf16* __restrict__ Alvl,    // (512,640) level features
    const __bf16* __restrict__ w2s,     // swizzled (2048x1152)
    const float* __restrict__ bias,     // 2048
    const int* __restrict__ mapping,    // level's (2,512)
    const __bf16* __restrict__ h_src, const float* __restrict__ c_src,
    __bf16* __restrict__ h_dst, float* __restrict__ c_dst,
    float* __restrict__ h_f32, int first)
{
  const int tid  = threadIdx.x;
  const int wv   = tid >> 6;
  const int lane = tid & 63;
  const int colq = lane & 15;
  const int quad = lane >> 4;
  const int jt = blockIdx.x;
  const int mt = blockIdx.y;
  const int rowA = mt * 64 + wv * 16 + colq;

  int i0 = 0, i1 = 0;
  if (!first) { i0 = mapping[rowA]; i1 = mapping[512 + rowA]; }
  const float s0 = (i0 > 0) ? 0.5f : 0.0f;
  const float s1 = (i1 > 0) ? 0.5f : 0.0f;
  const __bf16* h0p = h_src + (size_t)((i0 > 0 ? i0 : 1) - 1) * 512;
  const __bf16* h1p = h_src + (size_t)((i1 > 0 ? i1 : 1) - 1) * 512;

  f32x4 acc[4];
#pragma unroll
  for (int g = 0; g < 4; ++g)
#pragma unroll
    for (int r = 0; r < 4; ++r) acc[g][r] = 0.0f;

  const __bf16* wbase = w2s + (size_t)jt * 36 * 4 * 512 + (lane << 3);
  const __bf16* arow  = Alvl + (size_t)rowA * 640;

#pragma unroll 4
  for (int kk = 0; kk < 20; ++kk) {          // feature part of K
    const int kof = (kk << 5) + (quad << 3);
    bf16x8 afr = *(const bf16x8*)&arow[kof];
    bf16x8 b0 = *(const bf16x8*)&wbase[(kk * 4 + 0) << 9];
    bf16x8 b1 = *(const bf16x8*)&wbase[(kk * 4 + 1) << 9];
    bf16x8 b2 = *(const bf16x8*)&wbase[(kk * 4 + 2) << 9];
    bf16x8 b3 = *(const bf16x8*)&wbase[(kk * 4 + 3) << 9];
    acc[0] = __builtin_amdgcn_mfma_f32_16x16x32_bf16(afr, b0, acc[0], 0, 0, 0);
    acc[1] = __builtin_amdgcn_mfma_f32_16x16x32_bf16(afr, b1, acc[1], 0, 0, 0);
    acc[2] = __builtin_amdgcn_mfma_f32_16x16x32_bf16(afr, b2, acc[2], 0, 0, 0);
    acc[3] = __builtin_amdgcn_mfma_f32_16x16x32_bf16(afr, b3, acc[3], 0, 0, 0);
  }
#pragma unroll 4
  for (int kk = 20; kk < 36; ++kk) {         // gathered-h part of K
    const int kh = ((kk - 20) << 5) + (quad << 3);
    bf16x8 v0 = *(const bf16x8*)&h0p[kh];
    bf16x8 v1 = *(const bf16x8*)&h1p[kh];
    bf16x8 afr;
#pragma unroll
    for (int e = 0; e < 8; ++e)
      afr[e] = (__bf16)((float)v0[e] * s0 + (float)v1[e] * s1);
    bf16x8 b0 = *(const bf16x8*)&wbase[(kk * 4 + 0) << 9];
    bf16x8 b1 = *(const bf16x8*)&wbase[(kk * 4 + 1) << 9];
    bf16x8 b2 = *(const bf16x8*)&wbase[(kk * 4 + 2) << 9];
    bf16x8 b3 = *(const bf16x8*)&wbase[(kk * 4 + 3) << 9];
    acc[0] = __builtin_amdgcn_mfma_f32_16x16x32_bf16(afr, b0, acc[0], 0, 0, 0);
    acc[1] = __builtin_amdgcn_mfma_f32_16x16x32_bf16(afr, b1, acc[1], 0, 0, 0);
    acc[2] = __builtin_amdgcn_mfma_f32_16x16x32_bf16(afr, b2, acc[2], 0, 0, 0);
    acc[3] = __builtin_amdgcn_mfma_f32_16x16x32_bf16(afr, b3, acc[3], 0, 0, 0);
  }

  // epilogue: i,f,g,o -> c,h
  const int j = jt * 16 + colq;
  const float bi  = bias[j];
  const float bff = bias[512 + j];
  const float bg  = bias[1024 + j];
  const float bo  = bias[1536 + j];
#pragma unroll
  for (int r = 0; r < 4; ++r) {
    const int mrow = mt * 64 + wv * 16 + quad * 4 + r;
    float ci = 0.0f;
    if (!first) {
      int a0 = mapping[mrow], a1 = mapping[512 + mrow];
      if (a0 > 0) ci += c_src[(size_t)(a0 - 1) * 512 + j];
      if (a1 > 0) ci += c_src[(size_t)(a1 - 1) * 512 + j];
      ci *= 0.5f;
    }
    float c = fsig(acc[1][r] + bff) * ci + fsig(acc[0][r] + bi) * ftanh(acc[2][r] + bg);
    float h = fsig(acc[3][r] + bo) * ftanh(c);
    h_dst[(size_t)mrow * 512 + j] = (__bf16)h;
    c_dst[(size_t)mrow * 512 + j] = c;
    h_f32[(size_t)mrow * 512 + j] = h;
  }
}

// ---------------- batchnorm helpers ----------------
__global__ void stats1_kernel(const float* __restrict__ in, int ld, int N,
                              int rows_per_blk, float* __restrict__ partial)
{
  int b = blockIdx.x;
  int r0 = b * rows_per_blk;
  for (int c = threadIdx.x; c < N; c += blockDim.x) {
    float s = 0.0f, sq = 0.0f;
    for (int r = 0; r < rows_per_blk; ++r) {
      float v = in[(size_t)(r0 + r) * ld + c];
      s += v; sq += v * v;
    }
    partial[(size_t)(2 * b) * N + c] = s;
    partial[(size_t)(2 * b + 1) * N + c] = sq;
  }
}

__global__ void stats2_kernel(const float* __restrict__ partial, int nb, int N,
                              float invM, float* __restrict__ stats)
{
  int c = blockIdx.x * blockDim.x + threadIdx.x;
  if (c >= N) return;
  float s = 0.0f, sq = 0.0f;
  for (int b = 0; b < nb; ++b) {
    s  += partial[(size_t)(2 * b) * N + c];
    sq += partial[(size_t)(2 * b + 1) * N + c];
  }
  float mean = s * invM;
  float var  = sq * invM - mean * mean;
  stats[c]     = mean;
  stats[N + c] = rsqrtf(fmaxf(var, 0.0f) + 1e-5f);
}

__global__ void norm_kernel(const float* __restrict__ in, int ldin,
                            const float* __restrict__ stats, int N, int cshift, int gmask,
                            const float* __restrict__ g, const float* __restrict__ b,
                            __bf16* __restrict__ outp, int ldc, int total)
{
  for (int idx = blockIdx.x * blockDim.x + threadIdx.x; idx < total;
       idx += gridDim.x * blockDim.x) {
    int row = idx >> cshift;
    int c = idx & (N - 1);
    float v = (in[(size_t)row * ldin + c] - stats[c]) * stats[N + c];
    int gi = c & gmask;
    v = v * g[gi] + b[gi];
    outp[(size_t)row * ldc + c] = (__bf16)v;
  }
}

// ---------------- output heads ----------------
__global__ void head_kernel(const int* __restrict__ flagp,
                            const __bf16* __restrict__ tmp3,
                            const float* __restrict__ pf,
                            void* __restrict__ outp)
{
  const int bf = *flagp;
  int idx = blockIdx.x * blockDim.x + threadIdx.x;
  if (idx >= 1024) return;
  int which = idx >> 9;
  int n = idx & 511;
  const __bf16* row = tmp3 + (size_t)n * 512 + which * 256;
  const float* ow = pf + PF_OW + which * 256;
  float s = pf[PF_OB + which];
  for (int k = 0; k < 256; ++k) s += (float)row[k] * ow[k];
  float v = fsig(s);
  if (bf) ((__bf16*)outp)[idx] = (__bf16)v;
  else    ((float*)outp)[idx]  = v;
}

// ---------------- launch ----------------
extern "C" void kernel_launch(void* const* d_in, const int* in_sizes, int n_in,
                              void* d_out, int out_size, void* d_ws, size_t ws_size,
                              hipStream_t stream) {
  const void* operators       = d_in[0];
  const void* extra_infos     = d_in[1];
  const void* condition1s     = d_in[2];
  const void* samples         = d_in[4];
  const void* condition_masks = d_in[5];
  const int*  mapping         = (const int*)d_in[6];
  (void)in_sizes; (void)n_in; (void)out_size; (void)ws_size;

  char* ws = (char*)d_ws;
  size_t off = 0;
  auto alloc = [&](size_t bytes) -> void* {
    void* p = ws + off;
    off += (bytes + 255) & ~(size_t)255;
    return p;
  };
  int*    flag     = (int*)   alloc(256);
  __bf16* w1s      = (__bf16*)alloc((size_t)2048 * 544 * 2);
  __bf16* w2s      = (__bf16*)alloc((size_t)2048 * 1152 * 2);
  __bf16* wcat2    = (__bf16*)alloc(512 * 512 * 2);
  __bf16* cond_w_bf   = (__bf16*)alloc(256 * 512 * 2);
  __bf16* sample_w_bf = (__bf16*)alloc(256 * 1000 * 2);
  __bf16* w3cat_bf    = (__bf16*)alloc(512 * 256 * 2);
  float*  mask_f   = (float*) alloc(10240 * 4);
  float*  pf       = (float*) alloc(PF_TOTAL * 4);
  __bf16* samp_bf  = (__bf16*)alloc((size_t)10240 * 1000 * 2);
  __bf16* h_last   = (__bf16*)alloc((size_t)10272 * 512 * 2);
  float*  condtmp  = (float*) alloc((size_t)10240 * 256 * 4);
  __bf16* Astage   = (__bf16*)alloc((size_t)20 * 512 * 640 * 2);
  __bf16* hs0      = (__bf16*)alloc(512 * 512 * 2);
  __bf16* hs1      = (__bf16*)alloc(512 * 512 * 2);
  float*  cs0      = (float*) alloc(512 * 512 * 4);
  float*  cs1      = (float*) alloc(512 * 512 * 4);
  float*  h_f32    = (float*) alloc(512 * 512 * 4);
  __bf16* zbuf     = (__bf16*)alloc(512 * 512 * 2);
  float*  tmp1     = (float*) alloc(512 * 512 * 4);
  __bf16* tmp2     = (__bf16*)alloc(512 * 512 * 2);
  __bf16* tmp3     = (__bf16*)alloc(512 * 512 * 2);
  float*  partial  = (float*) alloc(64 * 2 * 512 * 4);
  float*  statsb   = (float*) alloc(2 * 512 * 4);

  detect_kernel<<<1, 64, 0, stream>>>((const unsigned*)condition_masks, flag);
  prep_kernel<<<4096, 256, 0, stream>>>(flag,
      d_in[7], d_in[8], d_in[9], d_in[10],
      d_in[17], d_in[18], d_in[19], d_in[20],
      d_in[23], d_in[25], d_in[24], d_in[26],
      d_in[13], d_in[14], d_in[11], d_in[12],
      d_in[15], d_in[16], d_in[21], d_in[22],
      d_in[27], d_in[28],
      d_in[29], d_in[30], d_in[31], d_in[32],
      d_in[33], d_in[34], d_in[35], d_in[36],
      condition_masks,
      w1s, w2s, wcat2, cond_w_bf, sample_w_bf, w3cat_bf, mask_f, pf);
  conv_samples_kernel<<<4096, 256, 0, stream>>>(flag, samples, samp_bf);
  featcopy_kernel<<<5120, 256, 0, stream>>>(flag, operators, extra_infos, Astage);
  lstm1_kernel<<<L1_BLOCKS, 512, 0, stream>>>(flag, condition1s, w1s, pf + PF_BIAS1, h_last);

  // cond = bn1(relu(h_last @ cond_w^T + cond_b)) -> Astage cols 123..378
  gemm_kernel<1,0,0><<<dim3(4,160), 256, 0, stream>>>(h_last, 512, cond_w_bf, 512,
      pf + PF_CONDB, condtmp, nullptr, 256, nullptr, 512);
  stats1_kernel<<<64, 256, 0, stream>>>(condtmp, 256, 256, 160, partial);
  stats2_kernel<<<1, 256, 0, stream>>>(partial, 64, 256, 1.0f / 10240.0f, statsb);
  norm_kernel<<<2560, 256, 0, stream>>>(condtmp, 256, statsb, 256, 8, 255,
      pf + PF_BN1G, pf + PF_BN1B, Astage + 123, 640, 10240 * 256);

  // samp = relu(samples @ sample_w^T + sample_b) * mask -> Astage cols 379..634
  sampgemm_kernel<<<dim3(4,160), 256, 0, stream>>>(flag, samples, samp_bf,
      sample_w_bf, pf + PF_SAMPB, Astage + 379, mask_f);

  // tree: lvl 19 (zero state) down to 0; ping-pong state by level parity
  for (int lvl = 19; lvl >= 0; --lvl) {
    __bf16* hd = (lvl & 1) ? hs1 : hs0;
    float*  cd = (lvl & 1) ? cs1 : cs0;
    const __bf16* hsrc = (lvl & 1) ? hs0 : hs1;
    const float*  csrc = (lvl & 1) ? cs0 : cs1;
    treelvl_kernel<<<dim3(32,8), 256, 0, stream>>>(
        Astage + (size_t)lvl * 512 * 640, w2s, pf + PF_BIAS2,
        mapping + lvl * 1024, hsrc, csrc, hd, cd, h_f32, (lvl == 19) ? 1 : 0);
  }

  // z = bn2(hid)
  stats1_kernel<<<8, 256, 0, stream>>>(h_f32, 512, 512, 64, partial);
  stats2_kernel<<<2, 256, 0, stream>>>(partial, 8, 512, 1.0f / 512.0f, statsb);
  norm_kernel<<<256, 256, 0, stream>>>(h_f32, 512, statsb, 512, 9, 511,
      pf + PF_BN2G, pf + PF_BN2B, zbuf, 512, 512 * 512);

  // [t1|t2] = bn3(relu(z @ [t1_w2;t2_w2]^T + b))
  gemm_kernel<1,0,0><<<dim3(8,8), 256, 0, stream>>>(zbuf, 512, wcat2, 512,
      pf + PF_BCAT2, tmp1, nullptr, 512, nullptr, 512);
  stats1_kernel<<<8, 256, 0, stream>>>(tmp1, 512, 512, 64, partial);
  stats2_kernel<<<2, 256, 0, stream>>>(partial, 8, 512, 1.0f / 512.0f, statsb);
  norm_kernel<<<256, 256, 0, stream>>>(tmp1, 512, statsb, 512, 9, 255,
      pf + PF_BN3G, pf + PF_BN3B, tmp2, 512, 512 * 512);

  // relu(t @ w3^T + b3) for both heads
  gemm_kernel<1,1,0><<<dim3(4,8), 256, 0, stream>>>(tmp2, 512, w3cat_bf, 256,
      pf + PF_B3CAT, nullptr, tmp3, 512, nullptr, 256);
  gemm_kernel<1,1,0><<<dim3(4,8), 256, 0, stream>>>(tmp2 + 256, 512, w3cat_bf + 256 * 256, 256,
      pf + PF_B3CAT + 256, nullptr, tmp3 + 256, 512, nullptr, 256);

  head_kernel<<<4, 256, 0, stream>>>(flag, tmp3, pf, d_out);
}

// Round 10
// 1080.221 us; speedup vs baseline: 3.2252x; 1.0680x over previous
//
#include <hip/hip_runtime.h>
#include <hip/hip_bf16.h>

// Representation_32074815766664 — bf16 I/O (runtime-detected f32 fallback),
// bf16 MFMA internally, f32 accumulation/state.
//
// R10 change vs R9 (1154 us; lstm1 397 us, VALUBusy 45.5%):
//  - fast gate math: fsig/ftanh via v_rcp_f32 (__builtin_amdgcn_rcpf) and
//    clamp-free robust forms (sig = rcp(1+exp(-x)); tanh = 2*sig(2x)-1).
//    R9's forms compiled to clamps + full-precision division (~8 inst) per
//    call; 240 transcendental calls per thread per lstm1 timestep made the
//    epilogue VALU work exceed the MFMA work. Everything else frozen.

typedef __bf16 bf16x8 __attribute__((ext_vector_type(8)));
typedef float f32x4 __attribute__((ext_vector_type(4)));

#define MROWS 10240
#define LDH1  552     // padded LDS stride (2-way bank aliasing only)
#define L1_ROWS 48
#define L1_BLOCKS 214 // ceil(10240/48)

// pf (canonical f32 params) offsets
#define PF_BIAS1   0
#define PF_BIAS2   2048
#define PF_CONDB   4096
#define PF_SAMPB   4352
#define PF_BCAT2   4608
#define PF_B3CAT   5120
#define PF_BN1G    5632
#define PF_BN1B    5888
#define PF_BN2G    6144
#define PF_BN2B    6656
#define PF_BN3G    7168
#define PF_BN3B    7424
#define PF_OW      7680
#define PF_OB      8192
#define PF_TOTAL   8194

// sig(x) = 1/(1+exp(-x)); robust without clamps: exp->inf => rcp->0.
__device__ __forceinline__ float fsig(float x) {
  return __builtin_amdgcn_rcpf(1.0f + __expf(-x));
}
// tanh(x) = 2*sig(2x) - 1; robust at both infinities.
__device__ __forceinline__ float ftanh(float x) {
  return fmaf(2.0f, __builtin_amdgcn_rcpf(1.0f + __expf(-2.0f * x)), -1.0f);
}
__device__ __forceinline__ bf16x8 bzero8() {
  bf16x8 z;
#pragma unroll
  for (int i = 0; i < 8; ++i) z[i] = (__bf16)0.0f;
  return z;
}
__device__ __forceinline__ float ld_in(const void* p, long i, int bf) {
  return bf ? (float)((const __bf16*)p)[i] : ((const float*)p)[i];
}

// ---------------- detect ----------------
__global__ void detect_kernel(const unsigned* __restrict__ masks, int* __restrict__ flag) {
  if (blockIdx.x == 0 && threadIdx.x == 0)
    *flag = (masks[0] == 0x3F803F80u) ? 1 : 0;
}

// ---------------- prep: canonicalize; w1s swizzled, w2s swizzled ----------------
// w1s: elem((cgt*17+kk)*4+g, lane, e) = w_aug1[g*512+cgt*16+(lane&15)][kk*32+(lane>>4)*8+e]
__global__ void prep_kernel(const int* __restrict__ flagp,
    const void* w_ih1, const void* w_hh1, const void* b_ih1, const void* b_hh1,
    const void* w_ih2, const void* w_hh2, const void* b_ih2, const void* b_hh2,
    const void* t1_w2, const void* t2_w2, const void* t1_b2, const void* t2_b2,
    const void* cond_w, const void* cond_b, const void* sample_w, const void* sample_b,
    const void* bn1_g, const void* bn1_b, const void* bn2_g, const void* bn2_b,
    const void* bn3_g, const void* bn3_b,
    const void* t1_w3, const void* t1_b3, const void* t2_w3, const void* t2_b3,
    const void* t1_ow, const void* t1_ob, const void* t2_ow, const void* t2_ob,
    const void* masks,
    __bf16* __restrict__ w1s, __bf16* __restrict__ w2s,
    __bf16* __restrict__ wcat2, __bf16* __restrict__ cond_w_bf,
    __bf16* __restrict__ sample_w_bf, __bf16* __restrict__ w3cat_bf,
    float* __restrict__ mask_f, float* __restrict__ pf)
{
  const int bf = *flagp;
  const int S1 = 2048 * 544;   // w1s swizzled
  const int S2 = 2048 * 1152;  // w2s swizzled
  const int S3 = 512 * 512;
  const int S4 = 256 * 512;
  const int S5 = 256 * 1000;
  const int S6 = 512 * 256;
  const int S7 = 10240;
  const int total = S1 + S2 + S3 + S4 + S5 + S6 + S7 + PF_TOTAL;
  for (int idx = blockIdx.x * blockDim.x + threadIdx.x; idx < total;
       idx += gridDim.x * blockDim.x) {
    int i = idx;
    if (i < S1) {
      int e = i & 7, l = (i >> 3) & 63, g = (i >> 9) & 3;
      int grp = i >> 11;               // cgt*17 + kk
      int kk = grp % 17, cgt = grp / 17;
      int colq = l & 15, quad = l >> 4;
      int row = g * 512 + cgt * 16 + colq;
      int k = kk * 32 + quad * 8 + e;
      float v = (k < 512) ? ld_in(w_hh1, (long)row * 512 + k, bf)
              : (k < 525) ? ld_in(w_ih1, (long)row * 13 + (k - 512), bf) : 0.0f;
      w1s[i] = (__bf16)v;
      continue;
    }
    i -= S1;
    if (i < S2) {
      int e = i & 7, l = (i >> 3) & 63, g = (i >> 9) & 3;
      int grp = i >> 11;               // jt*36 + kk
      int kk = grp % 36, jt = grp / 36;
      int colq = l & 15, quad = l >> 4;
      int row = g * 512 + jt * 16 + colq;
      int k = kk * 32 + quad * 8 + e;
      float v = (k < 635) ? ld_in(w_ih2, (long)row * 635 + k, bf)
              : (k < 640) ? 0.0f : ld_in(w_hh2, (long)row * 512 + (k - 640), bf);
      w2s[i] = (__bf16)v;
      continue;
    }
    i -= S2;
    if (i < S3) {
      int r = i >> 9, k = i & 511;
      wcat2[i] = (__bf16)((r < 256) ? ld_in(t1_w2, r * 512 + k, bf)
                                    : ld_in(t2_w2, (r - 256) * 512 + k, bf));
      continue;
    }
    i -= S3;
    if (i < S4) { cond_w_bf[i] = (__bf16)ld_in(cond_w, i, bf); continue; }
    i -= S4;
    if (i < S5) { sample_w_bf[i] = (__bf16)ld_in(sample_w, i, bf); continue; }
    i -= S5;
    if (i < S6) {
      int r = i >> 8, k = i & 255;
      w3cat_bf[i] = (__bf16)((r < 256) ? ld_in(t1_w3, r * 256 + k, bf)
                                       : ld_in(t2_w3, (r - 256) * 256 + k, bf));
      continue;
    }
    i -= S6;
    if (i < S7) { mask_f[i] = ld_in(masks, i, bf); continue; }
    i -= S7;
    {
      int j = i;
      float v;
      if      (j < 2048) v = ld_in(b_ih1, j, bf) + ld_in(b_hh1, j, bf);
      else if (j < 4096) v = ld_in(b_ih2, j - 2048, bf) + ld_in(b_hh2, j - 2048, bf);
      else if (j < 4352) v = ld_in(cond_b, j - 4096, bf);
      else if (j < 4608) v = ld_in(sample_b, j - 4352, bf);
      else if (j < 5120) { int k = j - 4608; v = (k < 256) ? ld_in(t1_b2, k, bf) : ld_in(t2_b2, k - 256, bf); }
      else if (j < 5632) { int k = j - 5120; v = (k < 256) ? ld_in(t1_b3, k, bf) : ld_in(t2_b3, k - 256, bf); }
      else if (j < 5888) v = ld_in(bn1_g, j - 5632, bf);
      else if (j < 6144) v = ld_in(bn1_b, j - 5888, bf);
      else if (j < 6656) v = ld_in(bn2_g, j - 6144, bf);
      else if (j < 7168) v = ld_in(bn2_b, j - 6656, bf);
      else if (j < 7424) v = ld_in(bn3_g, j - 7168, bf);
      else if (j < 7680) v = ld_in(bn3_b, j - 7424, bf);
      else if (j < 8192) { int k = j - 7680; v = (k < 256) ? ld_in(t1_ow, k, bf) : ld_in(t2_ow, k - 256, bf); }
      else v = (j == 8192) ? ld_in(t1_ob, 0, bf) : ld_in(t2_ob, 0, bf);
      pf[j] = v;
    }
  }
}

// ---------------- samples -> bf16 (only needed on f32 path) ----------------
__global__ void conv_samples_kernel(const int* __restrict__ flagp,
                                    const void* __restrict__ samples,
                                    __bf16* __restrict__ dst)
{
  const int bf = *flagp;
  if (bf) return;   // bf16 input is already the matrix the GEMM reads
  for (long i = blockIdx.x * blockDim.x + threadIdx.x; i < 10240000L;
       i += (long)gridDim.x * blockDim.x)
    dst[i] = (__bf16)ld_in(samples, i, bf);
}

// ---------------- featcopy (Astage stride 640) ----------------
__global__ void featcopy_kernel(const int* __restrict__ flagp,
                                const void* __restrict__ ops,
                                const void* __restrict__ extra,
                                __bf16* __restrict__ Astage)
{
  const int bf = *flagp;
  int idx = blockIdx.x * blockDim.x + threadIdx.x;  // exactly 10240*128
  int m = idx >> 7, c = idx & 127;
  float v; int col;
  if (c < 15)       { v = ld_in(ops, (long)m * 15 + c, bf);            col = c; }
  else if (c < 123) { v = ld_in(extra, (long)m * 108 + (c - 15), bf);  col = c; }
  else              { v = 0.0f;                                        col = 512 + c; } // 635..639
  Astage[(size_t)m * 640 + col] = (__bf16)v;
}

// ---------------- fused 10-step LSTM-1 — R9 structure, fast gate math ----------
// grid 214 x 512 threads (8 waves). Block owns 48 rows. Wave owns 64 hidden cols.
// hbuf[2]: augmented h[48][552]. One barrier per timestep.
__global__ __launch_bounds__(512, 2) void lstm1_kernel(
    const int* __restrict__ flagp,
    const void* __restrict__ cond1,     // (10240,10,13)
    const __bf16* __restrict__ w1s,     // swizzled (2048x544)
    const float*  __restrict__ bias,    // (2048)
    __bf16* __restrict__ h_out)         // (10272,512) padded
{
  __shared__ __attribute__((aligned(16))) __bf16 hbuf[2][L1_ROWS * LDH1];
  const int bf   = *flagp;
  const int tid  = threadIdx.x;
  const int wave = tid >> 6;
  const int lane = tid & 63;
  const int colq = lane & 15;
  const int quad = lane >> 4;
  const int r0   = blockIdx.x * L1_ROWS;

  {
    bf16x8 z8 = bzero8();
    for (int i = tid * 8; i < 2 * L1_ROWS * LDH1; i += 512 * 8)
      *(bf16x8*)&hbuf[0][i] = z8;
  }
  __syncthreads();
  if (tid < L1_ROWS * 8) {           // stage x_0 into buf 0
    int row = tid >> 3, jj = tid & 7;
    int gr = r0 + row;
    if (gr < MROWS) {
      long base = (long)gr * 130;  // t=0
      hbuf[0][row * LDH1 + 512 + jj] = (__bf16)ld_in(cond1, base + jj, bf);
      if (jj < 5) hbuf[0][row * LDH1 + 520 + jj] = (__bf16)ld_in(cond1, base + 8 + jj, bf);
    }
  }
  __syncthreads();

  float c_reg[4][3][4];
#pragma unroll
  for (int a = 0; a < 4; ++a)
#pragma unroll
    for (int b = 0; b < 3; ++b)
#pragma unroll
      for (int r = 0; r < 4; ++r) c_reg[a][b][r] = 0.0f;

  const int jbase = wave * 64;

  for (int t = 0; t < 10; ++t) {
    const __bf16* hcur = hbuf[t & 1];
    __bf16* hnxt = hbuf[(t + 1) & 1];
#pragma unroll
    for (int cg = 0; cg < 4; ++cg) {
      const int jc = jbase + cg * 16;
      f32x4 acc[3][4];
#pragma unroll
      for (int a = 0; a < 3; ++a)
#pragma unroll
        for (int g = 0; g < 4; ++g)
#pragma unroll
          for (int r = 0; r < 4; ++r) acc[a][g][r] = 0.0f;

      const __bf16* wp = w1s + ((size_t)(wave * 4 + cg) * 17 * 4 * 512) + (lane << 3);
#pragma unroll 1
      for (int kk = 0; kk < 17; ++kk) {
        const int kof = (kk << 5) + (quad << 3);
        bf16x8 af[3];
#pragma unroll
        for (int rt = 0; rt < 3; ++rt)
          af[rt] = *(const bf16x8*)&hcur[(rt * 16 + colq) * LDH1 + kof];
        bf16x8 bfr[4];
#pragma unroll
        for (int g = 0; g < 4; ++g)
          bfr[g] = *(const bf16x8*)&wp[(kk * 4 + g) << 9];
#pragma unroll
        for (int g = 0; g < 4; ++g)
#pragma unroll
          for (int rt = 0; rt < 3; ++rt)
            acc[rt][g] = __builtin_amdgcn_mfma_f32_16x16x32_bf16(af[rt], bfr[g], acc[rt][g], 0, 0, 0);
      }
      const float bi  = bias[jc + colq];
      const float bff = bias[512 + jc + colq];
      const float bg  = bias[1024 + jc + colq];
      const float bo  = bias[1536 + jc + colq];
#pragma unroll
      for (int rt = 0; rt < 3; ++rt)
#pragma unroll
        for (int r = 0; r < 4; ++r) {
          float c = fsig(acc[rt][1][r] + bff) * c_reg[cg][rt][r]
                  + fsig(acc[rt][0][r] + bi) * ftanh(acc[rt][2][r] + bg);
          c_reg[cg][rt][r] = c;
          float h = fsig(acc[rt][3][r] + bo) * ftanh(c);
          hnxt[(rt * 16 + quad * 4 + r) * LDH1 + jc + colq] = (__bf16)h;
        }
    }
    if (t < 9 && tid < L1_ROWS * 8) {   // stage x_{t+1} into next buffer
      int row = tid >> 3, jj = tid & 7;
      int gr = r0 + row;
      if (gr < MROWS) {
        long base = ((long)gr * 10 + (t + 1)) * 13;
        hnxt[row * LDH1 + 512 + jj] = (__bf16)ld_in(cond1, base + jj, bf);
        if (jj < 5) hnxt[row * LDH1 + 520 + jj] = (__bf16)ld_in(cond1, base + 8 + jj, bf);
      }
    }
    __syncthreads();
  }

  // final h is in buffer 0 (t=10 even)
  for (int i = tid; i < L1_ROWS * 64; i += 512) {
    int row = i >> 6;
    int cb  = (i & 63) << 3;
    *(bf16x8*)&h_out[(size_t)(r0 + row) * 512 + cb] = *(const bf16x8*)&hbuf[0][row * LDH1 + cb];
  }
}

// ---------------- generic MFMA GEMM: out = act(A @ W^T + bias) [* mask] ----------------
template<int ACT, int OUTBF, int MASKED>
__global__ __launch_bounds__(256, 4) void gemm_kernel(
    const __bf16* __restrict__ A, int lda,
    const __bf16* __restrict__ W, int ldw,
    const float* __restrict__ bias,
    float* __restrict__ outf, __bf16* __restrict__ outb, int ldc,
    const float* __restrict__ mask, int K)
{
  const int tid  = threadIdx.x;
  const int wave = tid >> 6;
  const int lane = tid & 63;
  const int colq = lane & 15;
  const int quad = lane >> 4;
  const int m0 = blockIdx.y * 64 + (wave >> 1) * 32;
  const int n0 = blockIdx.x * 64 + (wave & 1) * 32;

  f32x4 acc[2][2];
#pragma unroll
  for (int a = 0; a < 2; ++a)
#pragma unroll
    for (int b = 0; b < 2; ++b)
#pragma unroll
      for (int r = 0; r < 4; ++r) acc[a][b][r] = 0.0f;

  const int nk = (K + 31) >> 5;
  for (int kk = 0; kk < nk; ++kk) {
    const int kof = (kk << 5) + (quad << 3);
    bf16x8 a0, a1, b0, b1;
    if (kof < K) {
      a0 = *(const bf16x8*)&A[(size_t)(m0 + colq) * lda + kof];
      a1 = *(const bf16x8*)&A[(size_t)(m0 + 16 + colq) * lda + kof];
      b0 = *(const bf16x8*)&W[(size_t)(n0 + colq) * ldw + kof];
      b1 = *(const bf16x8*)&W[(size_t)(n0 + 16 + colq) * ldw + kof];
    } else {
      a0 = bzero8(); a1 = a0; b0 = a0; b1 = a0;
    }
    acc[0][0] = __builtin_amdgcn_mfma_f32_16x16x32_bf16(a0, b0, acc[0][0], 0, 0, 0);
    acc[0][1] = __builtin_amdgcn_mfma_f32_16x16x32_bf16(a0, b1, acc[0][1], 0, 0, 0);
    acc[1][0] = __builtin_amdgcn_mfma_f32_16x16x32_bf16(a1, b0, acc[1][0], 0, 0, 0);
    acc[1][1] = __builtin_amdgcn_mfma_f32_16x16x32_bf16(a1, b1, acc[1][1], 0, 0, 0);
  }
#pragma unroll
  for (int ai = 0; ai < 2; ++ai)
#pragma unroll
    for (int bi = 0; bi < 2; ++bi) {
      const int col = n0 + bi * 16 + colq;
      const float bv = bias[col];
#pragma unroll
      for (int r = 0; r < 4; ++r) {
        const int row = m0 + ai * 16 + quad * 4 + r;
        float v = acc[ai][bi][r] + bv;
        if (ACT) v = fmaxf(v, 0.0f);
        if (MASKED) v *= mask[row];
        if (OUTBF) outb[(size_t)row * ldc + col] = (__bf16)v;
        else       outf[(size_t)row * ldc + col] = v;
      }
    }
}

// ---------------- samples GEMM: A chosen by dtype flag ----------------
// out = relu(A @ W^T + b) * mask -> Astage cols 379..634 (ldc 640), K=1000.
__global__ __launch_bounds__(256, 4) void sampgemm_kernel(
    const int* __restrict__ flagp,
    const void* __restrict__ samples_raw,   // bf16 path reads this directly
    const __bf16* __restrict__ samp_bf,     // f32 path: converted copy
    const __bf16* __restrict__ W,
    const float* __restrict__ bias,
    __bf16* __restrict__ outb,
    const float* __restrict__ mask)
{
  const __bf16* A = (*flagp) ? (const __bf16*)samples_raw : samp_bf;
  const int tid  = threadIdx.x;
  const int wave = tid >> 6;
  const int lane = tid & 63;
  const int colq = lane & 15;
  const int quad = lane >> 4;
  const int m0 = blockIdx.y * 64 + (wave >> 1) * 32;
  const int n0 = blockIdx.x * 64 + (wave & 1) * 32;
  const int K = 1000;

  f32x4 acc[2][2];
#pragma unroll
  for (int a = 0; a < 2; ++a)
#pragma unroll
    for (int b = 0; b < 2; ++b)
#pragma unroll
      for (int r = 0; r < 4; ++r) acc[a][b][r] = 0.0f;

  for (int kk = 0; kk < 32; ++kk) {
    const int kof = (kk << 5) + (quad << 3);
    bf16x8 a0, a1, b0, b1;
    if (kof < K) {
      a0 = *(const bf16x8*)&A[(size_t)(m0 + colq) * 1000 + kof];
      a1 = *(const bf16x8*)&A[(size_t)(m0 + 16 + colq) * 1000 + kof];
      b0 = *(const bf16x8*)&W[(size_t)(n0 + colq) * 1000 + kof];
      b1 = *(const bf16x8*)&W[(size_t)(n0 + 16 + colq) * 1000 + kof];
    } else {
      a0 = bzero8(); a1 = a0; b0 = a0; b1 = a0;
    }
    acc[0][0] = __builtin_amdgcn_mfma_f32_16x16x32_bf16(a0, b0, acc[0][0], 0, 0, 0);
    acc[0][1] = __builtin_amdgcn_mfma_f32_16x16x32_bf16(a0, b1, acc[0][1], 0, 0, 0);
    acc[1][0] = __builtin_amdgcn_mfma_f32_16x16x32_bf16(a1, b0, acc[1][0], 0, 0, 0);
    acc[1][1] = __builtin_amdgcn_mfma_f32_16x16x32_bf16(a1, b1, acc[1][1], 0, 0, 0);
  }
#pragma unroll
  for (int ai = 0; ai < 2; ++ai)
#pragma unroll
    for (int bi = 0; bi < 2; ++bi) {
      const int col = n0 + bi * 16 + colq;
      const float bv = bias[col];
#pragma unroll
      for (int r = 0; r < 4; ++r) {
        const int row = m0 + ai * 16 + quad * 4 + r;
        float v = fmaxf(acc[ai][bi][r] + bv, 0.0f) * mask[row];
        outb[(size_t)row * 640 + col] = (__bf16)v;
      }
    }
}

// ---------------- fused tree level: gather + GEMM(K=1152) + cell update ----------------
__global__ __launch_bounds__(256, 4) void treelvl_kernel(
    const __bf16* __restrict__ Alvl,    // (512,640) level features
    const __bf16* __restrict__ w2s,     // swizzled (2048x1152)
    const float* __restrict__ bias,     // 2048
    const int* __restrict__ mapping,    // level's (2,512)
    const __bf16* __restrict__ h_src, const float* __restrict__ c_src,
    __bf16* __restrict__ h_dst, float* __restrict__ c_dst,
    float* __restrict__ h_f32, int first)
{
  const int tid  = threadIdx.x;
  const int wv   = tid >> 6;
  const int lane = tid & 63;
  const int colq = lane & 15;
  const int quad = lane >> 4;
  const int jt = blockIdx.x;
  const int mt = blockIdx.y;
  const int rowA = mt * 64 + wv * 16 + colq;

  int i0 = 0, i1 = 0;
  if (!first) { i0 = mapping[rowA]; i1 = mapping[512 + rowA]; }
  const float s0 = (i0 > 0) ? 0.5f : 0.0f;
  const float s1 = (i1 > 0) ? 0.5f : 0.0f;
  const __bf16* h0p = h_src + (size_t)((i0 > 0 ? i0 : 1) - 1) * 512;
  const __bf16* h1p = h_src + (size_t)((i1 > 0 ? i1 : 1) - 1) * 512;

  f32x4 acc[4];
#pragma unroll
  for (int g = 0; g < 4; ++g)
#pragma unroll
    for (int r = 0; r < 4; ++r) acc[g][r] = 0.0f;

  const __bf16* wbase = w2s + (size_t)jt * 36 * 4 * 512 + (lane << 3);
  const __bf16* arow  = Alvl + (size_t)rowA * 640;

#pragma unroll 4
  for (int kk = 0; kk < 20; ++kk) {          // feature part of K
    const int kof = (kk << 5) + (quad << 3);
    bf16x8 afr = *(const bf16x8*)&arow[kof];
    bf16x8 b0 = *(const bf16x8*)&wbase[(kk * 4 + 0) << 9];
    bf16x8 b1 = *(const bf16x8*)&wbase[(kk * 4 + 1) << 9];
    bf16x8 b2 = *(const bf16x8*)&wbase[(kk * 4 + 2) << 9];
    bf16x8 b3 = *(const bf16x8*)&wbase[(kk * 4 + 3) << 9];
    acc[0] = __builtin_amdgcn_mfma_f32_16x16x32_bf16(afr, b0, acc[0], 0, 0, 0);
    acc[1] = __builtin_amdgcn_mfma_f32_16x16x32_bf16(afr, b1, acc[1], 0, 0, 0);
    acc[2] = __builtin_amdgcn_mfma_f32_16x16x32_bf16(afr, b2, acc[2], 0, 0, 0);
    acc[3] = __builtin_amdgcn_mfma_f32_16x16x32_bf16(afr, b3, acc[3], 0, 0, 0);
  }
#pragma unroll 4
  for (int kk = 20; kk < 36; ++kk) {         // gathered-h part of K
    const int kh = ((kk - 20) << 5) + (quad << 3);
    bf16x8 v0 = *(const bf16x8*)&h0p[kh];
    bf16x8 v1 = *(const bf16x8*)&h1p[kh];
    bf16x8 afr;
#pragma unroll
    for (int e = 0; e < 8; ++e)
      afr[e] = (__bf16)((float)v0[e] * s0 + (float)v1[e] * s1);
    bf16x8 b0 = *(const bf16x8*)&wbase[(kk * 4 + 0) << 9];
    bf16x8 b1 = *(const bf16x8*)&wbase[(kk * 4 + 1) << 9];
    bf16x8 b2 = *(const bf16x8*)&wbase[(kk * 4 + 2) << 9];
    bf16x8 b3 = *(const bf16x8*)&wbase[(kk * 4 + 3) << 9];
    acc[0] = __builtin_amdgcn_mfma_f32_16x16x32_bf16(afr, b0, acc[0], 0, 0, 0);
    acc[1] = __builtin_amdgcn_mfma_f32_16x16x32_bf16(afr, b1, acc[1], 0, 0, 0);
    acc[2] = __builtin_amdgcn_mfma_f32_16x16x32_bf16(afr, b2, acc[2], 0, 0, 0);
    acc[3] = __builtin_amdgcn_mfma_f32_16x16x32_bf16(afr, b3, acc[3], 0, 0, 0);
  }

  // epilogue: i,f,g,o -> c,h
  const int j = jt * 16 + colq;
  const float bi  = bias[j];
  const float bff = bias[512 + j];
  const float bg  = bias[1024 + j];
  const float bo  = bias[1536 + j];
#pragma unroll
  for (int r = 0; r < 4; ++r) {
    const int mrow = mt * 64 + wv * 16 + quad * 4 + r;
    float ci = 0.0f;
    if (!first) {
      int a0 = mapping[mrow], a1 = mapping[512 + mrow];
      if (a0 > 0) ci += c_src[(size_t)(a0 - 1) * 512 + j];
      if (a1 > 0) ci += c_src[(size_t)(a1 - 1) * 512 + j];
      ci *= 0.5f;
    }
    float c = fsig(acc[1][r] + bff) * ci + fsig(acc[0][r] + bi) * ftanh(acc[2][r] + bg);
    float h = fsig(acc[3][r] + bo) * ftanh(c);
    h_dst[(size_t)mrow * 512 + j] = (__bf16)h;
    c_dst[(size_t)mrow * 512 + j] = c;
    h_f32[(size_t)mrow * 512 + j] = h;
  }
}

// ---------------- batchnorm helpers ----------------
__global__ void stats1_kernel(const float* __restrict__ in, int ld, int N,
                              int rows_per_blk, float* __restrict__ partial)
{
  int b = blockIdx.x;
  int r0 = b * rows_per_blk;
  for (int c = threadIdx.x; c < N; c += blockDim.x) {
    float s = 0.0f, sq = 0.0f;
    for (int r = 0; r < rows_per_blk; ++r) {
      float v = in[(size_t)(r0 + r) * ld + c];
      s += v; sq += v * v;
    }
    partial[(size_t)(2 * b) * N + c] = s;
    partial[(size_t)(2 * b + 1) * N + c] = sq;
  }
}

__global__ void stats2_kernel(const float* __restrict__ partial, int nb, int N,
                              float invM, float* __restrict__ stats)
{
  int c = blockIdx.x * blockDim.x + threadIdx.x;
  if (c >= N) return;
  float s = 0.0f, sq = 0.0f;
  for (int b = 0; b < nb; ++b) {
    s  += partial[(size_t)(2 * b) * N + c];
    sq += partial[(size_t)(2 * b + 1) * N + c];
  }
  float mean = s * invM;
  float var  = sq * invM - mean * mean;
  stats[c]     = mean;
  stats[N + c] = rsqrtf(fmaxf(var, 0.0f) + 1e-5f);
}

__global__ void norm_kernel(const float* __restrict__ in, int ldin,
                            const float* __restrict__ stats, int N, int cshift, int gmask,
                            const float* __restrict__ g, const float* __restrict__ b,
                            __bf16* __restrict__ outp, int ldc, int total)
{
  for (int idx = blockIdx.x * blockDim.x + threadIdx.x; idx < total;
       idx += gridDim.x * blockDim.x) {
    int row = idx >> cshift;
    int c = idx & (N - 1);
    float v = (in[(size_t)row * ldin + c] - stats[c]) * stats[N + c];
    int gi = c & gmask;
    v = v * g[gi] + b[gi];
    outp[(size_t)row * ldc + c] = (__bf16)v;
  }
}

// ---------------- output heads ----------------
__global__ void head_kernel(const int* __restrict__ flagp,
                            const __bf16* __restrict__ tmp3,
                            const float* __restrict__ pf,
                            void* __restrict__ outp)
{
  const int bf = *flagp;
  int idx = blockIdx.x * blockDim.x + threadIdx.x;
  if (idx >= 1024) return;
  int which = idx >> 9;
  int n = idx & 511;
  const __bf16* row = tmp3 + (size_t)n * 512 + which * 256;
  const float* ow = pf + PF_OW + which * 256;
  float s = pf[PF_OB + which];
  for (int k = 0; k < 256; ++k) s += (float)row[k] * ow[k];
  float v = fsig(s);
  if (bf) ((__bf16*)outp)[idx] = (__bf16)v;
  else    ((float*)outp)[idx]  = v;
}

// ---------------- launch ----------------
extern "C" void kernel_launch(void* const* d_in, const int* in_sizes, int n_in,
                              void* d_out, int out_size, void* d_ws, size_t ws_size,
                              hipStream_t stream) {
  const void* operators       = d_in[0];
  const void* extra_infos     = d_in[1];
  const void* condition1s     = d_in[2];
  const void* samples         = d_in[4];
  const void* condition_masks = d_in[5];
  const int*  mapping         = (const int*)d_in[6];
  (void)in_sizes; (void)n_in; (void)out_size; (void)ws_size;

  char* ws = (char*)d_ws;
  size_t off = 0;
  auto alloc = [&](size_t bytes) -> void* {
    void* p = ws + off;
    off += (bytes + 255) & ~(size_t)255;
    return p;
  };
  int*    flag     = (int*)   alloc(256);
  __bf16* w1s      = (__bf16*)alloc((size_t)2048 * 544 * 2);
  __bf16* w2s      = (__bf16*)alloc((size_t)2048 * 1152 * 2);
  __bf16* wcat2    = (__bf16*)alloc(512 * 512 * 2);
  __bf16* cond_w_bf   = (__bf16*)alloc(256 * 512 * 2);
  __bf16* sample_w_bf = (__bf16*)alloc(256 * 1000 * 2);
  __bf16* w3cat_bf    = (__bf16*)alloc(512 * 256 * 2);
  float*  mask_f   = (float*) alloc(10240 * 4);
  float*  pf       = (float*) alloc(PF_TOTAL * 4);
  __bf16* samp_bf  = (__bf16*)alloc((size_t)10240 * 1000 * 2);
  __bf16* h_last   = (__bf16*)alloc((size_t)10272 * 512 * 2);
  float*  condtmp  = (float*) alloc((size_t)10240 * 256 * 4);
  __bf16* Astage   = (__bf16*)alloc((size_t)20 * 512 * 640 * 2);
  __bf16* hs0      = (__bf16*)alloc(512 * 512 * 2);
  __bf16* hs1      = (__bf16*)alloc(512 * 512 * 2);
  float*  cs0      = (float*) alloc(512 * 512 * 4);
  float*  cs1      = (float*) alloc(512 * 512 * 4);
  float*  h_f32    = (float*) alloc(512 * 512 * 4);
  __bf16* zbuf     = (__bf16*)alloc(512 * 512 * 2);
  float*  tmp1     = (float*) alloc(512 * 512 * 4);
  __bf16* tmp2     = (__bf16*)alloc(512 * 512 * 2);
  __bf16* tmp3     = (__bf16*)alloc(512 * 512 * 2);
  float*  partial  = (float*) alloc(64 * 2 * 512 * 4);
  float*  statsb   = (float*) alloc(2 * 512 * 4);

  detect_kernel<<<1, 64, 0, stream>>>((const unsigned*)condition_masks, flag);
  prep_kernel<<<4096, 256, 0, stream>>>(flag,
      d_in[7], d_in[8], d_in[9], d_in[10],
      d_in[17], d_in[18], d_in[19], d_in[20],
      d_in[23], d_in[25], d_in[24], d_in[26],
      d_in[13], d_in[14], d_in[11], d_in[12],
      d_in[15], d_in[16], d_in[21], d_in[22],
      d_in[27], d_in[28],
      d_in[29], d_in[30], d_in[31], d_in[32],
      d_in[33], d_in[34], d_in[35], d_in[36],
      condition_masks,
      w1s, w2s, wcat2, cond_w_bf, sample_w_bf, w3cat_bf, mask_f, pf);
  conv_samples_kernel<<<4096, 256, 0, stream>>>(flag, samples, samp_bf);
  featcopy_kernel<<<5120, 256, 0, stream>>>(flag, operators, extra_infos, Astage);
  lstm1_kernel<<<L1_BLOCKS, 512, 0, stream>>>(flag, condition1s, w1s, pf + PF_BIAS1, h_last);

  // cond = bn1(relu(h_last @ cond_w^T + cond_b)) -> Astage cols 123..378
  gemm_kernel<1,0,0><<<dim3(4,160), 256, 0, stream>>>(h_last, 512, cond_w_bf, 512,
      pf + PF_CONDB, condtmp, nullptr, 256, nullptr, 512);
  stats1_kernel<<<64, 256, 0, stream>>>(condtmp, 256, 256, 160, partial);
  stats2_kernel<<<1, 256, 0, stream>>>(partial, 64, 256, 1.0f / 10240.0f, statsb);
  norm_kernel<<<2560, 256, 0, stream>>>(condtmp, 256, statsb, 256, 8, 255,
      pf + PF_BN1G, pf + PF_BN1B, Astage + 123, 640, 10240 * 256);

  // samp = relu(samples @ sample_w^T + sample_b) * mask -> Astage cols 379..634
  sampgemm_kernel<<<dim3(4,160), 256, 0, stream>>>(flag, samples, samp_bf,
      sample_w_bf, pf + PF_SAMPB, Astage + 379, mask_f);

  // tree: lvl 19 (zero state) down to 0; ping-pong state by level parity
  for (int lvl = 19; lvl >= 0; --lvl) {
    __bf16* hd = (lvl & 1) ? hs1 : hs0;
    float*  cd = (lvl & 1) ? cs1 : cs0;
    const __bf16* hsrc = (lvl & 1) ? hs0 : hs1;
    const float*  csrc = (lvl & 1) ? cs0 : cs1;
    treelvl_kernel<<<dim3(32,8), 256, 0, stream>>>(
        Astage + (size_t)lvl * 512 * 640, w2s, pf + PF_BIAS2,
        mapping + lvl * 1024, hsrc, csrc, hd, cd, h_f32, (lvl == 19) ? 1 : 0);
  }

  // z = bn2(hid)
  stats1_kernel<<<8, 256, 0, stream>>>(h_f32, 512, 512, 64, partial);
  stats2_kernel<<<2, 256, 0, stream>>>(partial, 8, 512, 1.0f / 512.0f, statsb);
  norm_kernel<<<256, 256, 0, stream>>>(h_f32, 512, statsb, 512, 9, 511,
      pf + PF_BN2G, pf + PF_BN2B, zbuf, 512, 512 * 512);

  // [t1|t2] = bn3(relu(z @ [t1_w2;t2_w2]^T + b))
  gemm_kernel<1,0,0><<<dim3(8,8), 256, 0, stream>>>(zbuf, 512, wcat2, 512,
      pf + PF_BCAT2, tmp1, nullptr, 512, nullptr, 512);
  stats1_kernel<<<8, 256, 0, stream>>>(tmp1, 512, 512, 64, partial);
  stats2_kernel<<<2, 256, 0, stream>>>(partial, 8, 512, 1.0f / 512.0f, statsb);
  norm_kernel<<<256, 256, 0, stream>>>(tmp1, 512, statsb, 512, 9, 255,
      pf + PF_BN3G, pf + PF_BN3B, tmp2, 512, 512 * 512);

  // relu(t @ w3^T + b3) for both heads
  gemm_kernel<1,1,0><<<dim3(4,8), 256, 0, stream>>>(tmp2, 512, w3cat_bf, 256,
      pf + PF_B3CAT, nullptr, tmp3, 512, nullptr, 256);
  gemm_kernel<1,1,0><<<dim3(4,8), 256, 0, stream>>>(tmp2 + 256, 512, w3cat_bf + 256 * 256, 256,
      pf + PF_B3CAT + 256, nullptr, tmp3 + 256, 512, nullptr, 256);

  head_kernel<<<4, 256, 0, stream>>>(flag, tmp3, pf, d_out);
}